// Round 2
// 811.644 us; speedup vs baseline: 2.4849x; 2.4849x over previous
//
#include <hip/hip_runtime.h>
#include <hip/hip_bf16.h>
#include <math.h>

// Problem constants (B=4, 128x128 grid, DIM=256, 8 heads x 64)
#define NB 4
#define NY 128
#define NX 128
#define DIM 256
#define NH 8
#define DH_ 64
#define HDIM 512   // NH*DH
#define HID 1024
#define NPOS (NB*NY*NX)   // 65536

typedef __hip_bfloat16 bf16_t;
typedef __attribute__((ext_vector_type(8))) short short8;   // 8 bf16 = 1 MFMA A/B frag
typedef __attribute__((ext_vector_type(4))) float f32x4;    // MFMA C/D frag

__device__ __forceinline__ float b2f(bf16_t x){ return __bfloat162float(x); }
__device__ __forceinline__ bf16_t f2b(float x){ return __float2bfloat16(x); }
__device__ __forceinline__ short f2s(float x){ bf16_t h = __float2bfloat16(x); return *reinterpret_cast<short*>(&h); }
__device__ __forceinline__ float s2f(short x){ bf16_t h = *reinterpret_cast<bf16_t*>(&x); return __bfloat162float(h); }

// MFMA fragment layout (gfx950, verified in-round 3->4):
//  A[m][k]: m = lane&15, k = (lane>>4)*8 + j
//  B[k][n]: n = lane&15, k = (lane>>4)*8 + j
//  D[row][col]: col = lane&15, row = (lane>>4)*4 + reg

__device__ __forceinline__ float gelu_tanh(float x){
  float x3 = x*x*x;
  return 0.5f*x*(1.0f + tanhf(0.7978845608028654f*(x + 0.044715f*x3)));
}

// ---------------------------------------------------------------- weight pack
// W[K x N] f32 row-major -> bf16 B-fragment order
__global__ void __launch_bounds__(256) k_pack(const float* __restrict__ W,
    short* __restrict__ out, int K, int N){
  int tid = blockIdx.x*256 + threadIdx.x;      // < K*N/8
  int lane = tid & 63;
  int rem = tid >> 6;
  int ntiles = N >> 4;
  int nt = rem % ntiles, kb = rem / ntiles;
  int n = nt*16 + (lane & 15);
  int k0 = kb*32 + (lane>>4)*8;
  short8 v;
  #pragma unroll
  for (int j=0;j<8;j++) v[j] = f2s(W[(size_t)(k0+j)*N + n]);
  *(short8*)&out[(size_t)tid*8] = v;
}

// ---------------------------------------------------------------- LN1 (f32 in -> bf16 un)
__global__ void __launch_bounds__(256) k_ln1(const float* __restrict__ u,
    const float* __restrict__ g, const float* __restrict__ b,
    bf16_t* __restrict__ un){
  int wave = threadIdx.x >> 6, lane = threadIdx.x & 63;
  size_t row = (size_t)blockIdx.x*4 + wave;
  const float* x = u + row*DIM;
  float v[4]; float s=0.f, ss=0.f;
  #pragma unroll
  for (int j=0;j<4;j++){ float t = x[lane + j*64]; v[j]=t; s+=t; ss+=t*t; }
  #pragma unroll
  for (int off=32;off>0;off>>=1){ s += __shfl_down(s,off,64); ss += __shfl_down(ss,off,64); }
  s = __shfl(s,0,64); ss = __shfl(ss,0,64);
  float m = s*(1.0f/DIM);
  float var = ss*(1.0f/DIM) - m*m;
  float r = rsqrtf(var + 1e-5f);
  bf16_t* o = un + row*DIM;
  #pragma unroll
  for (int j=0;j<4;j++){
    int f = lane + j*64;
    o[f] = f2b((v[j]-m)*r*g[f] + b[f]);
  }
}

// ---------------------------------------------------------------- pooling (bf16 un -> f32)
__global__ void __launch_bounds__(256) k_pool_y(const bf16_t* __restrict__ un, float* __restrict__ pooly){
  int by = blockIdx.x;
  int d = threadIdx.x;
  size_t base = (size_t)by*NX*DIM + d;
  float s = 0.f;
  for (int x=0;x<NX;x++) s += b2f(un[base + (size_t)x*DIM]);
  pooly[(size_t)by*DIM + d] = s*(1.0f/NX);
}
__global__ void __launch_bounds__(256) k_pool_x(const bf16_t* __restrict__ un, float* __restrict__ poolx){
  int bb = blockIdx.x / NX, x = blockIdx.x % NX;
  int d = threadIdx.x;
  size_t base = ((size_t)bb*NY*NX + x)*DIM + d;
  float s = 0.f;
  for (int y=0;y<NY;y++) s += b2f(un[base + (size_t)y*NX*DIM]);
  poolx[(size_t)blockIdx.x*DIM + d] = s*(1.0f/NY);
}

// ---------------------------------------------------------------- MFMA GEMM for the small chain
// C[M x N] = op(A[M x K] @ W + bias); A f32 (bf16-staged), W packed bf16 frags,
// f32 MFMA accumulate, f32 out. grid = (M/64, N/256), block 256.
#define GS_STRIDE 72
__global__ void __launch_bounds__(256) k_gemm_mfma(const float* __restrict__ A,
    const short* __restrict__ WP, const float* __restrict__ bias,
    float* __restrict__ C, int N, int K, int dogelu){
  __shared__ __align__(16) short As[64*GS_STRIDE];   // 9.2 KB
  int tid = threadIdx.x;
  int lane = tid & 63, w = tid >> 6;
  int am = lane & 15, aq = lane >> 4;
  int m0 = blockIdx.x*64;
  int nt0 = blockIdx.y*16;          // n-tile offset (16 tiles of 16 cols = 256 cols/block)
  int ntiles = N >> 4;
  f32x4 o[4][4];
  #pragma unroll
  for (int mt=0;mt<4;mt++)
    #pragma unroll
    for (int nt=0;nt<4;nt++) o[mt][nt] = (f32x4){0.f,0.f,0.f,0.f};

  for (int kc=0; kc<K; kc+=64){
    // stage A[m0..+64][kc..+64] f32 -> bf16 LDS (64x64, 1024 float4s, 4/thread)
    #pragma unroll
    for (int it=0; it<4; it++){
      int q = tid + it*256;
      int r = q >> 4, c4 = q & 15;
      float4 v = *(const float4*)&A[(size_t)(m0+r)*K + kc + c4*4];
      ushort4 p;
      p.x = (ushort)f2s(v.x); p.y = (ushort)f2s(v.y);
      p.z = (ushort)f2s(v.z); p.w = (ushort)f2s(v.w);
      *(ushort4*)&As[r*GS_STRIDE + c4*4] = p;
    }
    __syncthreads();
    #pragma unroll
    for (int kb=0; kb<2; kb++){
      short8 a[4], bfr[4];
      #pragma unroll
      for (int mt=0;mt<4;mt++)
        a[mt] = *(const short8*)&As[(mt*16+am)*GS_STRIDE + kb*32 + aq*8];
      int kbg = (kc>>5) + kb;
      #pragma unroll
      for (int nt=0;nt<4;nt++){
        int ntg = nt0 + w*4 + nt;
        bfr[nt] = *(const short8*)&WP[(size_t)((kbg*ntiles + ntg)*64 + lane)*8];
      }
      #pragma unroll
      for (int mt=0;mt<4;mt++)
        #pragma unroll
        for (int nt=0;nt<4;nt++)
          o[mt][nt] = __builtin_amdgcn_mfma_f32_16x16x32_bf16(a[mt], bfr[nt], o[mt][nt], 0,0,0);
    }
    __syncthreads();
  }

  #pragma unroll
  for (int nt=0;nt<4;nt++){
    int col = (nt0 + w*4 + nt)*16 + am;
    float bv = bias ? bias[col] : 0.f;
    #pragma unroll
    for (int mt=0;mt<4;mt++){
      #pragma unroll
      for (int reg=0;reg<4;reg++){
        int row = m0 + mt*16 + aq*4 + reg;
        float val = o[mt][nt][reg] + bv;
        if (dogelu) val = gelu_tanh(val);
        C[(size_t)row*N + col] = val;
      }
    }
  }
}

// ---------------------------------------------------------------- RoPE split
__global__ void __launch_bounds__(256) k_rope(const float* __restrict__ qk,
    const float* __restrict__ cs, const float* __restrict__ sn,
    float* __restrict__ q, float* __restrict__ k){
  int idx = blockIdx.x*256 + threadIdx.x;
  int c = idx & 63;
  int h = (idx>>6) & 7;
  int p = (idx>>9) & 1;
  int n = (idx>>10) & 127;
  int bb = idx>>17;
  float t = qk[idx];
  float t2 = qk[(c<32) ? idx+32 : idx-32];
  if (c<32) t2 = -t2;
  float val = t*cs[n*64+c] + t2*sn[n*64+c];
  float* dst = p ? k : q;
  dst[(((size_t)bb*NH + h)*128 + n)*64 + c] = val;
}

// ---------------------------------------------------------------- attention matrix (bf16 out)
__global__ void __launch_bounds__(128) k_attn(const float* __restrict__ q,
    const float* __restrict__ k, bf16_t* __restrict__ attn){
  int i = blockIdx.x & 127;
  int bh = blockIdx.x >> 7;
  __shared__ float qs[64];
  __shared__ float sm[128];
  int tid = threadIdx.x;
  const float* qrow = q + ((size_t)bh*128 + i)*64;
  if (tid < 64) qs[tid] = qrow[tid];
  __syncthreads();
  const float* krow = k + ((size_t)bh*128 + tid)*64;
  float dot = 0.f;
  for (int c=0;c<64;c++) dot += qs[c]*krow[c];
  dot *= (1.0f/64.0f);
  sm[tid] = dot;
  __syncthreads();
  float mx = -1e30f;
  for (int j=0;j<128;j++) mx = fmaxf(mx, sm[j]);
  __syncthreads();
  float e = expf(dot - mx);
  sm[tid] = e;
  __syncthreads();
  float s = 0.f;
  for (int j=0;j<128;j++) s += sm[j];
  attn[(size_t)blockIdx.x*128 + tid] = f2b(e/s);
}

// ---------------------------------------------------------------- MFMA phi1: V-proj + y-attention
// block (bh, m=x): V[y][c] = un[b,y,m,:] @ Wv[:, h*64+c]  (K=256, MFMA)
//                  P1[i][c] = attnY[bh,i,:] @ V[:,c]      (K=128, MFMA)
// phi layout out: [bh][i][m][c]
#define AST 136   // 128 + 8 shorts
#define UST 72    // 64 + 8 shorts
#define VST 136
__global__ void __launch_bounds__(256) k_phi1m(const bf16_t* __restrict__ un,
    const short* __restrict__ WvP, const bf16_t* __restrict__ attn,
    bf16_t* __restrict__ phi){
  int m  = blockIdx.x & (NX-1);
  int bh = blockIdx.x >> 7;
  int b  = bh >> 3, h = bh & 7;
  __shared__ __align__(16) short At[128*AST];   // 34.8 KB
  __shared__ __align__(16) short unc[128*UST];  // 18.4 KB
  __shared__ __align__(16) short Vt[64*VST];    // 17.4 KB  [c][y]
  int tid = threadIdx.x;
  int lane = tid & 63, w = tid >> 6;
  int am = lane & 15, aq = lane >> 4;

  // stage attn slice (bh): 128x128 bf16 -> At (read only in phase 2)
  {
    const ushort* ag = (const ushort*)attn + (size_t)bh*16384;
    #pragma unroll
    for (int it=0; it<16; it++){
      int q = tid + it*256;          // < 4096 ushort4
      int i = q >> 5, j4 = q & 31;
      *(ushort4*)&At[i*AST + j4*4] = *(const ushort4*)(ag + i*128 + j4*4);
    }
  }

  // ---- phase 1: V-projection (wave w owns y rows w*32..+31, all 64 c)
  f32x4 v[2][4];
  #pragma unroll
  for (int mt=0;mt<2;mt++)
    #pragma unroll
    for (int nt=0;nt<4;nt++) v[mt][nt] = (f32x4){0.f,0.f,0.f,0.f};
  const ushort* ug = (const ushort*)un;
  for (int kc=0; kc<4; kc++){
    #pragma unroll
    for (int it=0; it<8; it++){
      int q = tid + it*256;          // < 2048 ushort4
      int y = q >> 4, c4 = q & 15;
      *(ushort4*)&unc[y*UST + c4*4] =
          *(const ushort4*)(ug + (((size_t)b*NY + y)*NX + m)*DIM + kc*64 + c4*4);
    }
    __syncthreads();
    #pragma unroll
    for (int kb=0; kb<2; kb++){
      short8 a2[2], bb[4];
      #pragma unroll
      for (int mt=0;mt<2;mt++)
        a2[mt] = *(const short8*)&unc[(w*32 + mt*16 + am)*UST + kb*32 + aq*8];
      int kbg = kc*2 + kb;           // of 8
      #pragma unroll
      for (int nt=0;nt<4;nt++)
        bb[nt] = *(const short8*)&WvP[(size_t)((kbg*32 + (h*4+nt))*64 + lane)*8];
      #pragma unroll
      for (int mt=0;mt<2;mt++)
        #pragma unroll
        for (int nt=0;nt<4;nt++)
          v[mt][nt] = __builtin_amdgcn_mfma_f32_16x16x32_bf16(a2[mt], bb[nt], v[mt][nt], 0,0,0);
    }
    __syncthreads();
  }
  // V frags -> Vt transposed [c][y] (4 consecutive y per frag -> ushort4)
  #pragma unroll
  for (int mt=0;mt<2;mt++)
    #pragma unroll
    for (int nt=0;nt<4;nt++){
      int c = nt*16 + am;
      int y0 = w*32 + mt*16 + aq*4;
      ushort4 pk;
      pk.x = (ushort)f2s(v[mt][nt][0]);
      pk.y = (ushort)f2s(v[mt][nt][1]);
      pk.z = (ushort)f2s(v[mt][nt][2]);
      pk.w = (ushort)f2s(v[mt][nt][3]);
      *(ushort4*)&Vt[c*VST + y0] = pk;
    }
  __syncthreads();

  // ---- phase 2: P1 = attnY @ V (rows i = w*32..+31, cols 64 c, K=128)
  f32x4 o[2][4];
  #pragma unroll
  for (int mt=0;mt<2;mt++)
    #pragma unroll
    for (int nt=0;nt<4;nt++) o[mt][nt] = (f32x4){0.f,0.f,0.f,0.f};
  #pragma unroll
  for (int kb=0; kb<4; kb++){
    short8 a2[2], bb[4];
    #pragma unroll
    for (int mt=0;mt<2;mt++)
      a2[mt] = *(const short8*)&At[(w*32 + mt*16 + am)*AST + kb*32 + aq*8];
    #pragma unroll
    for (int nt=0;nt<4;nt++)
      bb[nt] = *(const short8*)&Vt[(nt*16 + am)*VST + kb*32 + aq*8];
    #pragma unroll
    for (int mt=0;mt<2;mt++)
      #pragma unroll
      for (int nt=0;nt<4;nt++)
        o[mt][nt] = __builtin_amdgcn_mfma_f32_16x16x32_bf16(a2[mt], bb[nt], o[mt][nt], 0,0,0);
  }
  // write P1 -> phi[bh][i][m][c]
  ushort* pg = (ushort*)phi + (size_t)bh*NY*NX*DH_ + (size_t)m*DH_;
  #pragma unroll
  for (int mt=0;mt<2;mt++)
    #pragma unroll
    for (int nt=0;nt<4;nt++)
      #pragma unroll
      for (int reg=0;reg<4;reg++){
        int i = w*32 + mt*16 + aq*4 + reg;
        int c = nt*16 + am;
        pg[(size_t)i*(NX*DH_) + c] = (ushort)f2s(o[mt][nt][reg]);
      }
}

// ---------------------------------------------------------------- MFMA phi2: x-attention, in place
// block (bh, i): P2[l][c] = attnX[bh,l,:] @ P1[i,:,c]; slice [m][c] -> Pt[c][m]
__global__ void __launch_bounds__(256) k_phi2m(const bf16_t* __restrict__ attn,
    bf16_t* __restrict__ phi){
  int i  = blockIdx.x & (NY-1);
  int bh = blockIdx.x >> 7;
  __shared__ __align__(16) short Ax[128*AST];   // 34.8 KB
  __shared__ __align__(16) short Pt[64*VST];    // 17.4 KB  [c][m]
  int tid = threadIdx.x;
  int lane = tid & 63, w = tid >> 6;
  int am = lane & 15, aq = lane >> 4;

  {
    const ushort* ag = (const ushort*)attn + (size_t)bh*16384;
    #pragma unroll
    for (int it=0; it<16; it++){
      int q = tid + it*256;
      int r = q >> 5, j4 = q & 31;
      *(ushort4*)&Ax[r*AST + j4*4] = *(const ushort4*)(ag + r*128 + j4*4);
    }
  }
  ushort* pg = (ushort*)phi + (size_t)(bh*NY + i)*(NX*DH_);
  // slice is 128x64 shorts = 2048 ushort4 -> 8 iterations
  #pragma unroll
  for (int it=0; it<8; it++){
    int q = tid + it*256;            // < 2048 ushort4
    int mm = q >> 4, c4 = q & 15;    // mm in [0,128), c4 in [0,16)
    ushort4 v4 = *(const ushort4*)(pg + mm*DH_ + c4*4);
    Pt[(c4*4+0)*VST + mm] = v4.x;
    Pt[(c4*4+1)*VST + mm] = v4.y;
    Pt[(c4*4+2)*VST + mm] = v4.z;
    Pt[(c4*4+3)*VST + mm] = v4.w;
  }
  __syncthreads();

  f32x4 o[2][4];
  #pragma unroll
  for (int mt=0;mt<2;mt++)
    #pragma unroll
    for (int nt=0;nt<4;nt++) o[mt][nt] = (f32x4){0.f,0.f,0.f,0.f};
  #pragma unroll
  for (int kb=0; kb<4; kb++){
    short8 a2[2], bb[4];
    #pragma unroll
    for (int mt=0;mt<2;mt++)
      a2[mt] = *(const short8*)&Ax[(w*32 + mt*16 + am)*AST + kb*32 + aq*8];
    #pragma unroll
    for (int nt=0;nt<4;nt++)
      bb[nt] = *(const short8*)&Pt[(nt*16 + am)*VST + kb*32 + aq*8];
    #pragma unroll
    for (int mt=0;mt<2;mt++)
      #pragma unroll
      for (int nt=0;nt<4;nt++)
        o[mt][nt] = __builtin_amdgcn_mfma_f32_16x16x32_bf16(a2[mt], bb[nt], o[mt][nt], 0,0,0);
  }
  // write P2 in place: phi[bh][i][l][c]
  #pragma unroll
  for (int mt=0;mt<2;mt++)
    #pragma unroll
    for (int nt=0;nt<4;nt++)
      #pragma unroll
      for (int reg=0;reg<4;reg++){
        int l = w*32 + mt*16 + aq*4 + reg;
        int c = nt*16 + am;
        pg[(size_t)l*DH_ + c] = (ushort)f2s(o[mt][nt][reg]);
      }
}

// ---------------------------------------------------------------- GroupNorm + Wm + residual (MFMA)
#define GN_STRIDE 520
__global__ void __launch_bounds__(256) k_gn_wm(const bf16_t* __restrict__ phi,
    const short* __restrict__ WmP, const float* __restrict__ bm,
    const float* __restrict__ u, float* __restrict__ u2){
  __shared__ __align__(16) short X[64*GN_STRIDE];
  __shared__ float mean_s[512], rstd_s[512];
  int tid = threadIdx.x;
  int lane = tid & 63, w = tid >> 6;
  size_t p0 = (size_t)blockIdx.x*64;
  int b  = (int)(p0 >> 14);
  int y  = (int)((p0 >> 7) & 127);
  int x0 = (int)(p0 & 127);

  #pragma unroll
  for (int it=0; it<32; it++){
    int q = tid + it*256;
    int r = q >> 7, f4 = q & 127;
    int h = f4 >> 4, c4 = f4 & 15;
    const ushort* src = (const ushort*)phi +
        ((((size_t)b*NH + h)*NY + y)*NX + (x0 + r))*DH_ + c4*4;
    *(ushort4*)&X[r*GN_STRIDE + f4*4] = *(const ushort4*)src;
  }
  __syncthreads();
  #pragma unroll
  for (int gg=0; gg<2; gg++){
    int g = tid*2 + gg;
    int r = g >> 3, h = g & 7;
    const short* base = &X[r*GN_STRIDE + h*64];
    float s=0.f, ss=0.f;
    #pragma unroll
    for (int i=0;i<16;i++){
      ushort4 v4 = *(const ushort4*)&base[i*4];
      float a = s2f((short)v4.x), bq = s2f((short)v4.y), cq = s2f((short)v4.z), d = s2f((short)v4.w);
      s += a+bq+cq+d; ss += a*a+bq*bq+cq*cq+d*d;
    }
    float mm = s*(1.0f/64.0f);
    float vv = ss*(1.0f/64.0f) - mm*mm;
    mean_s[g] = mm;
    rstd_s[g] = rsqrtf(vv + 1e-6f);
  }
  __syncthreads();
  #pragma unroll
  for (int it=0; it<32; it++){
    int q = tid + it*256;
    int r = q >> 7, f4 = q & 127;
    int h = f4 >> 4;
    float mm = mean_s[r*8 + h], rs = rstd_s[r*8 + h];
    short* ptr = &X[r*GN_STRIDE + f4*4];
    ushort4 v4 = *(ushort4*)ptr;
    v4.x = (ushort)f2s((s2f((short)v4.x)-mm)*rs);
    v4.y = (ushort)f2s((s2f((short)v4.y)-mm)*rs);
    v4.z = (ushort)f2s((s2f((short)v4.z)-mm)*rs);
    v4.w = (ushort)f2s((s2f((short)v4.w)-mm)*rs);
    *(ushort4*)ptr = v4;
  }
  __syncthreads();

  f32x4 o[4][4];
  #pragma unroll
  for (int mt=0;mt<4;mt++)
    #pragma unroll
    for (int nt=0;nt<4;nt++) o[mt][nt] = (f32x4){0.f,0.f,0.f,0.f};
  int am = lane & 15, aq = lane >> 4;
  for (int kb=0; kb<16; kb++){
    short8 a[4], bfr[4];
    #pragma unroll
    for (int mt=0;mt<4;mt++)
      a[mt] = *(const short8*)&X[(mt*16 + am)*GN_STRIDE + kb*32 + aq*8];
    #pragma unroll
    for (int nt=0;nt<4;nt++)
      bfr[nt] = *(const short8*)&WmP[(size_t)((kb*16 + (w*4+nt))*64 + lane)*8];
    #pragma unroll
    for (int mt=0;mt<4;mt++)
      #pragma unroll
      for (int nt=0;nt<4;nt++)
        o[mt][nt] = __builtin_amdgcn_mfma_f32_16x16x32_bf16(a[mt], bfr[nt], o[mt][nt], 0,0,0);
  }
  #pragma unroll
  for (int nt=0;nt<4;nt++){
    int col = w*64 + nt*16 + am;
    float bmv = bm[col];
    #pragma unroll
    for (int mt=0;mt<4;mt++){
      #pragma unroll
      for (int reg=0;reg<4;reg++){
        size_t p = p0 + mt*16 + aq*4 + reg;
        u2[p*DIM + col] = o[mt][nt][reg] + bmv + u[p*DIM + col];
      }
    }
  }
}

// ---------------------------------------------------------------- LN2 + MLP + residual (MFMA, in-place in d_out)
#define ML_STRIDE 264
__global__ void __launch_bounds__(256) k_mlp_out(float* u2,
    const float* __restrict__ g2, const float* __restrict__ b2,
    const short* __restrict__ Wf1P, const float* __restrict__ bf1,
    const short* __restrict__ Wf2P, const float* __restrict__ bf2){
  __shared__ __align__(16) short X[64*ML_STRIDE];
  __shared__ __align__(16) short H[64*ML_STRIDE];
  int tid = threadIdx.x;
  int lane = tid & 63, w = tid >> 6;
  size_t p0 = (size_t)blockIdx.x*64;

  float4 g4 = *(const float4*)&g2[lane*4];
  float4 bq4 = *(const float4*)&b2[lane*4];
  for (int rr=0; rr<16; rr++){
    int r = w*16 + rr;
    float4 v = *(const float4*)&u2[(p0 + r)*DIM + lane*4];
    float s = v.x+v.y+v.z+v.w;
    float ss = v.x*v.x+v.y*v.y+v.z*v.z+v.w*v.w;
    #pragma unroll
    for (int off=32;off>0;off>>=1){ s += __shfl_down(s,off,64); ss += __shfl_down(ss,off,64); }
    s = __shfl(s,0,64); ss = __shfl(ss,0,64);
    float m = s*(1.0f/DIM);
    float rstd = rsqrtf(ss*(1.0f/DIM) - m*m + 1e-5f);
    ushort4 xo;
    xo.x = (ushort)f2s((v.x-m)*rstd*g4.x + bq4.x);
    xo.y = (ushort)f2s((v.y-m)*rstd*g4.y + bq4.y);
    xo.z = (ushort)f2s((v.z-m)*rstd*g4.z + bq4.z);
    xo.w = (ushort)f2s((v.w-m)*rstd*g4.w + bq4.w);
    *(ushort4*)&X[r*ML_STRIDE + lane*4] = xo;
  }
  __syncthreads();

  int am = lane & 15, aq = lane >> 4;
  f32x4 o[4][4];
  #pragma unroll
  for (int mt=0;mt<4;mt++)
    #pragma unroll
    for (int nt=0;nt<4;nt++) o[mt][nt] = (f32x4){0.f,0.f,0.f,0.f};

  for (int nc=0; nc<4; nc++){
    f32x4 hacc[4][4];
    #pragma unroll
    for (int mt=0;mt<4;mt++)
      #pragma unroll
      for (int nt=0;nt<4;nt++) hacc[mt][nt] = (f32x4){0.f,0.f,0.f,0.f};
    for (int kb=0; kb<8; kb++){
      short8 a[4], bfr[4];
      #pragma unroll
      for (int mt=0;mt<4;mt++)
        a[mt] = *(const short8*)&X[(mt*16 + am)*ML_STRIDE + kb*32 + aq*8];
      #pragma unroll
      for (int nt=0;nt<4;nt++){
        int ntg = nc*16 + w*4 + nt;
        bfr[nt] = *(const short8*)&Wf1P[(size_t)((kb*64 + ntg)*64 + lane)*8];
      }
      #pragma unroll
      for (int mt=0;mt<4;mt++)
        #pragma unroll
        for (int nt=0;nt<4;nt++)
          hacc[mt][nt] = __builtin_amdgcn_mfma_f32_16x16x32_bf16(a[mt], bfr[nt], hacc[mt][nt], 0,0,0);
    }
    #pragma unroll
    for (int nt=0;nt<4;nt++){
      int col_l = w*64 + nt*16 + am;
      float bv = bf1[nc*256 + col_l];
      #pragma unroll
      for (int mt=0;mt<4;mt++){
        #pragma unroll
        for (int reg=0;reg<4;reg++){
          int row = mt*16 + aq*4 + reg;
          H[row*ML_STRIDE + col_l] = f2s(gelu_tanh(hacc[mt][nt][reg] + bv));
        }
      }
    }
    __syncthreads();
    for (int kb=0; kb<8; kb++){
      short8 a[4], bfr[4];
      #pragma unroll
      for (int mt=0;mt<4;mt++)
        a[mt] = *(const short8*)&H[(mt*16 + am)*ML_STRIDE + kb*32 + aq*8];
      int kbg = nc*8 + kb;
      #pragma unroll
      for (int nt=0;nt<4;nt++)
        bfr[nt] = *(const short8*)&Wf2P[(size_t)((kbg*16 + (w*4+nt))*64 + lane)*8];
      #pragma unroll
      for (int mt=0;mt<4;mt++)
        #pragma unroll
        for (int nt=0;nt<4;nt++)
          o[mt][nt] = __builtin_amdgcn_mfma_f32_16x16x32_bf16(a[mt], bfr[nt], o[mt][nt], 0,0,0);
    }
    __syncthreads();
  }

  #pragma unroll
  for (int nt=0;nt<4;nt++){
    int col = w*64 + nt*16 + am;
    float bv = bf2[col];
    #pragma unroll
    for (int mt=0;mt<4;mt++){
      #pragma unroll
      for (int reg=0;reg<4;reg++){
        size_t p = p0 + mt*16 + aq*4 + reg;
        float res = u2[p*DIM + col];
        u2[p*DIM + col] = o[mt][nt][reg] + bv + res;
      }
    }
  }
}

extern "C" void kernel_launch(void* const* d_in, const int* in_sizes, int n_in,
                              void* d_out, int out_size, void* d_ws, size_t ws_size,
                              hipStream_t stream){
  const float* u    = (const float*)d_in[0];
  const float* rcy  = (const float*)d_in[1];
  const float* rsy  = (const float*)d_in[2];
  const float* rcx  = (const float*)d_in[3];
  const float* rsx  = (const float*)d_in[4];
  const float* ln1g = (const float*)d_in[6];
  const float* ln1b = (const float*)d_in[7];
  const float* ln2g = (const float*)d_in[8];
  const float* ln2b = (const float*)d_in[9];
  const float* Wv   = (const float*)d_in[10];
  const float* Wyin = (const float*)d_in[11];
  const float* Wy1  = (const float*)d_in[12];
  const float* by1  = (const float*)d_in[13];
  const float* Wy2  = (const float*)d_in[14];
  const float* by2  = (const float*)d_in[15];
  const float* Wxin = (const float*)d_in[16];
  const float* Wx1  = (const float*)d_in[17];
  const float* bx1  = (const float*)d_in[18];
  const float* Wx2  = (const float*)d_in[19];
  const float* bx2  = (const float*)d_in[20];
  const float* Wqkx = (const float*)d_in[21];
  const float* Wqky = (const float*)d_in[22];
  const float* Wm   = (const float*)d_in[23];
  const float* bm   = (const float*)d_in[24];
  const float* Wf1  = (const float*)d_in[25];
  const float* bf1  = (const float*)d_in[26];
  const float* Wf2  = (const float*)d_in[27];
  const float* bf2  = (const float*)d_in[28];

  char* w = (char*)d_ws;
  auto alloc = [&](size_t n) -> void* {
    void* p = (void*)w;
    w += (n + 255) & ~(size_t)255;
    return p;
  };
  bf16_t* UN   = (bf16_t*)alloc((size_t)NPOS*DIM*2);               // 32 MiB
  bf16_t* PHI  = (bf16_t*)alloc((size_t)NB*NH*NY*NX*DH_*2);        // 64 MiB
  float* POOLY = (float*)alloc((size_t)NB*NY*DIM*4);
  float* POOLX = (float*)alloc((size_t)NB*NX*DIM*4);
  float* TY    = (float*)alloc((size_t)512*256*4);
  float* TX    = (float*)alloc((size_t)512*256*4);
  float* HY    = (float*)alloc((size_t)512*1024*4);
  float* HX    = (float*)alloc((size_t)512*1024*4);
  float* UY    = (float*)alloc((size_t)512*256*4);
  float* UX    = (float*)alloc((size_t)512*256*4);
  float* QKY   = (float*)alloc((size_t)512*1024*4);
  float* QKX   = (float*)alloc((size_t)512*1024*4);
  float* QRY   = (float*)alloc((size_t)NB*NH*128*64*4);
  float* KRY   = (float*)alloc((size_t)NB*NH*128*64*4);
  float* QRX   = (float*)alloc((size_t)NB*NH*128*64*4);
  float* KRX   = (float*)alloc((size_t)NB*NH*128*64*4);
  bf16_t* ATTNY = (bf16_t*)alloc((size_t)NB*NH*128*128*2);
  bf16_t* ATTNX = (bf16_t*)alloc((size_t)NB*NH*128*128*2);
  short* WF1P  = (short*)alloc((size_t)256*1024*2);
  short* WF2P  = (short*)alloc((size_t)1024*256*2);
  short* WMP   = (short*)alloc((size_t)512*256*2);
  short* WVP   = (short*)alloc((size_t)256*512*2);
  short* WYINP = (short*)alloc((size_t)256*256*2);
  short* WY1P  = (short*)alloc((size_t)256*1024*2);
  short* WY2P  = (short*)alloc((size_t)1024*256*2);
  short* WQKYP = (short*)alloc((size_t)256*1024*2);
  short* WXINP = (short*)alloc((size_t)256*256*2);
  short* WX1P  = (short*)alloc((size_t)256*1024*2);
  short* WX2P  = (short*)alloc((size_t)1024*256*2);
  short* WQKXP = (short*)alloc((size_t)256*1024*2);
  float* U2 = (float*)d_out;
  (void)in_sizes; (void)n_in; (void)out_size; (void)ws_size;

  k_pack<<<(256*1024/8)/256, 256, 0, stream>>>(Wf1, WF1P, 256, 1024);
  k_pack<<<(1024*256/8)/256, 256, 0, stream>>>(Wf2, WF2P, 1024, 256);
  k_pack<<<(512*256/8)/256, 256, 0, stream>>>(Wm, WMP, 512, 256);
  k_pack<<<(256*512/8)/256, 256, 0, stream>>>(Wv, WVP, 256, 512);
  k_pack<<<(256*256/8)/256, 256, 0, stream>>>(Wyin, WYINP, 256, 256);
  k_pack<<<(256*1024/8)/256, 256, 0, stream>>>(Wy1, WY1P, 256, 1024);
  k_pack<<<(1024*256/8)/256, 256, 0, stream>>>(Wy2, WY2P, 1024, 256);
  k_pack<<<(256*1024/8)/256, 256, 0, stream>>>(Wqky, WQKYP, 256, 1024);
  k_pack<<<(256*256/8)/256, 256, 0, stream>>>(Wxin, WXINP, 256, 256);
  k_pack<<<(256*1024/8)/256, 256, 0, stream>>>(Wx1, WX1P, 256, 1024);
  k_pack<<<(1024*256/8)/256, 256, 0, stream>>>(Wx2, WX2P, 1024, 256);
  k_pack<<<(256*1024/8)/256, 256, 0, stream>>>(Wqkx, WQKXP, 256, 1024);

  k_ln1<<<NPOS/4, 256, 0, stream>>>(u, ln1g, ln1b, UN);
  k_pool_y<<<NB*NY, 256, 0, stream>>>(UN, POOLY);
  k_pool_x<<<NB*NX, 256, 0, stream>>>(UN, POOLX);

  // y chain: pool -> Win -> gelu-MLP -> QK   (M=512 rows, MFMA)
  k_gemm_mfma<<<dim3(8,1), 256, 0, stream>>>(POOLY, WYINP, (const float*)nullptr, TY, 256, 256, 0);
  k_gemm_mfma<<<dim3(8,4), 256, 0, stream>>>(TY, WY1P, by1, HY, 1024, 256, 1);
  k_gemm_mfma<<<dim3(8,1), 256, 0, stream>>>(HY, WY2P, by2, UY, 256, 1024, 0);
  k_gemm_mfma<<<dim3(8,4), 256, 0, stream>>>(UY, WQKYP, (const float*)nullptr, QKY, 1024, 256, 0);
  // x chain
  k_gemm_mfma<<<dim3(8,1), 256, 0, stream>>>(POOLX, WXINP, (const float*)nullptr, TX, 256, 256, 0);
  k_gemm_mfma<<<dim3(8,4), 256, 0, stream>>>(TX, WX1P, bx1, HX, 1024, 256, 1);
  k_gemm_mfma<<<dim3(8,1), 256, 0, stream>>>(HX, WX2P, bx2, UX, 256, 1024, 0);
  k_gemm_mfma<<<dim3(8,4), 256, 0, stream>>>(UX, WQKXP, (const float*)nullptr, QKX, 1024, 256, 0);

  k_rope<<<(NB*128*1024)/256, 256, 0, stream>>>(QKY, rcy, rsy, QRY, KRY);
  k_rope<<<(NB*128*1024)/256, 256, 0, stream>>>(QKX, rcx, rsx, QRX, KRX);
  k_attn<<<NB*NH*128, 128, 0, stream>>>(QRY, KRY, ATTNY);
  k_attn<<<NB*NH*128, 128, 0, stream>>>(QRX, KRX, ATTNX);
  k_phi1m<<<NB*NH*NX, 256, 0, stream>>>(UN, WVP, ATTNY, PHI);
  k_phi2m<<<NB*NH*NY, 256, 0, stream>>>(ATTNX, PHI);
  k_gn_wm<<<NPOS/64, 256, 0, stream>>>(PHI, WMP, bm, u, U2);
  k_mlp_out<<<NPOS/64, 256, 0, stream>>>(U2, ln2g, ln2b, WF1P, bf1, WF2P, bf2);
}

// Round 3
// 712.260 us; speedup vs baseline: 2.8317x; 1.1395x over previous
//
#include <hip/hip_runtime.h>
#include <hip/hip_bf16.h>
#include <math.h>

// Problem constants (B=4, 128x128 grid, DIM=256, 8 heads x 64)
#define NB 4
#define NY 128
#define NX 128
#define DIM 256
#define NH 8
#define DH_ 64
#define HDIM 512   // NH*DH
#define HID 1024
#define NPOS (NB*NY*NX)   // 65536

typedef __hip_bfloat16 bf16_t;
typedef __attribute__((ext_vector_type(8))) short short8;   // 8 bf16 = 1 MFMA A/B frag
typedef __attribute__((ext_vector_type(4))) float f32x4;    // MFMA C/D frag

__device__ __forceinline__ float b2f(bf16_t x){ return __bfloat162float(x); }
__device__ __forceinline__ bf16_t f2b(float x){ return __float2bfloat16(x); }
__device__ __forceinline__ short f2s(float x){ bf16_t h = __float2bfloat16(x); return *reinterpret_cast<short*>(&h); }
__device__ __forceinline__ float s2f(short x){ bf16_t h = *reinterpret_cast<bf16_t*>(&x); return __bfloat162float(h); }

// MFMA fragment layout (gfx950, verified in-round 3->4):
//  A[m][k]: m = lane&15, k = (lane>>4)*8 + j
//  B[k][n]: n = lane&15, k = (lane>>4)*8 + j
//  D[row][col]: col = lane&15, row = (lane>>4)*4 + reg

// gelu tanh-approx: 0.5x(1+tanh(t)) == x*sigmoid(2t); __expf maps to v_exp_f32.
__device__ __forceinline__ float gelu_tanh(float x){
  float z = 1.5957691216057308f*(x + 0.044715f*x*x*x);   // 2*0.79788456*(x+0.044715x^3)
  return x / (1.0f + __expf(-z));
}

// ---------------------------------------------------------------- weight pack
// W[K x N] f32 row-major -> bf16 B-fragment order
__global__ void __launch_bounds__(256) k_pack(const float* __restrict__ W,
    short* __restrict__ out, int K, int N){
  int tid = blockIdx.x*256 + threadIdx.x;      // < K*N/8
  int lane = tid & 63;
  int rem = tid >> 6;
  int ntiles = N >> 4;
  int nt = rem % ntiles, kb = rem / ntiles;
  int n = nt*16 + (lane & 15);
  int k0 = kb*32 + (lane>>4)*8;
  short8 v;
  #pragma unroll
  for (int j=0;j<8;j++) v[j] = f2s(W[(size_t)(k0+j)*N + n]);
  *(short8*)&out[(size_t)tid*8] = v;
}

// ---------------------------------------------------------------- LN1 (f32 in -> bf16 un)
__global__ void __launch_bounds__(256) k_ln1(const float* __restrict__ u,
    const float* __restrict__ g, const float* __restrict__ b,
    bf16_t* __restrict__ un){
  int wave = threadIdx.x >> 6, lane = threadIdx.x & 63;
  size_t row = (size_t)blockIdx.x*4 + wave;
  const float* x = u + row*DIM;
  float v[4]; float s=0.f, ss=0.f;
  #pragma unroll
  for (int j=0;j<4;j++){ float t = x[lane + j*64]; v[j]=t; s+=t; ss+=t*t; }
  #pragma unroll
  for (int off=32;off>0;off>>=1){ s += __shfl_down(s,off,64); ss += __shfl_down(ss,off,64); }
  s = __shfl(s,0,64); ss = __shfl(ss,0,64);
  float m = s*(1.0f/DIM);
  float var = ss*(1.0f/DIM) - m*m;
  float r = rsqrtf(var + 1e-5f);
  bf16_t* o = un + row*DIM;
  #pragma unroll
  for (int j=0;j<4;j++){
    int f = lane + j*64;
    o[f] = f2b((v[j]-m)*r*g[f] + b[f]);
  }
}

// ---------------------------------------------------------------- pooling (bf16 un -> f32)
__global__ void __launch_bounds__(256) k_pool_y(const bf16_t* __restrict__ un, float* __restrict__ pooly){
  int by = blockIdx.x;
  int d = threadIdx.x;
  size_t base = (size_t)by*NX*DIM + d;
  float s = 0.f;
  for (int x=0;x<NX;x++) s += b2f(un[base + (size_t)x*DIM]);
  pooly[(size_t)by*DIM + d] = s*(1.0f/NX);
}
__global__ void __launch_bounds__(256) k_pool_x(const bf16_t* __restrict__ un, float* __restrict__ poolx){
  int bb = blockIdx.x / NX, x = blockIdx.x % NX;
  int d = threadIdx.x;
  size_t base = ((size_t)bb*NY*NX + x)*DIM + d;
  float s = 0.f;
  for (int y=0;y<NY;y++) s += b2f(un[base + (size_t)y*NX*DIM]);
  poolx[(size_t)blockIdx.x*DIM + d] = s*(1.0f/NY);
}

// ---------------------------------------------------------------- MFMA GEMM for the small chain
// C[M x N] = op(A[M x K] @ W + bias); A f32 (bf16-staged), W packed bf16 frags,
// f32 MFMA accumulate, f32 out. grid = (M/64, N/256), block 256.
#define GS_STRIDE 72
__global__ void __launch_bounds__(256) k_gemm_mfma(const float* __restrict__ A,
    const short* __restrict__ WP, const float* __restrict__ bias,
    float* __restrict__ C, int N, int K, int dogelu){
  __shared__ __align__(16) short As[64*GS_STRIDE];   // 9.2 KB
  int tid = threadIdx.x;
  int lane = tid & 63, w = tid >> 6;
  int am = lane & 15, aq = lane >> 4;
  int m0 = blockIdx.x*64;
  int nt0 = blockIdx.y*16;          // n-tile offset (16 tiles of 16 cols = 256 cols/block)
  int ntiles = N >> 4;
  f32x4 o[4][4];
  #pragma unroll
  for (int mt=0;mt<4;mt++)
    #pragma unroll
    for (int nt=0;nt<4;nt++) o[mt][nt] = (f32x4){0.f,0.f,0.f,0.f};

  for (int kc=0; kc<K; kc+=64){
    // stage A[m0..+64][kc..+64] f32 -> bf16 LDS (64x64, 1024 float4s, 4/thread)
    #pragma unroll
    for (int it=0; it<4; it++){
      int q = tid + it*256;
      int r = q >> 4, c4 = q & 15;
      float4 v = *(const float4*)&A[(size_t)(m0+r)*K + kc + c4*4];
      ushort4 p;
      p.x = (ushort)f2s(v.x); p.y = (ushort)f2s(v.y);
      p.z = (ushort)f2s(v.z); p.w = (ushort)f2s(v.w);
      *(ushort4*)&As[r*GS_STRIDE + c4*4] = p;
    }
    __syncthreads();
    #pragma unroll
    for (int kb=0; kb<2; kb++){
      short8 a[4], bfr[4];
      #pragma unroll
      for (int mt=0;mt<4;mt++)
        a[mt] = *(const short8*)&As[(mt*16+am)*GS_STRIDE + kb*32 + aq*8];
      int kbg = (kc>>5) + kb;
      #pragma unroll
      for (int nt=0;nt<4;nt++){
        int ntg = nt0 + w*4 + nt;
        bfr[nt] = *(const short8*)&WP[(size_t)((kbg*ntiles + ntg)*64 + lane)*8];
      }
      #pragma unroll
      for (int mt=0;mt<4;mt++)
        #pragma unroll
        for (int nt=0;nt<4;nt++)
          o[mt][nt] = __builtin_amdgcn_mfma_f32_16x16x32_bf16(a[mt], bfr[nt], o[mt][nt], 0,0,0);
    }
    __syncthreads();
  }

  #pragma unroll
  for (int nt=0;nt<4;nt++){
    int col = (nt0 + w*4 + nt)*16 + am;
    float bv = bias ? bias[col] : 0.f;
    #pragma unroll
    for (int mt=0;mt<4;mt++){
      #pragma unroll
      for (int reg=0;reg<4;reg++){
        int row = m0 + mt*16 + aq*4 + reg;
        float val = o[mt][nt][reg] + bv;
        if (dogelu) val = gelu_tanh(val);
        C[(size_t)row*N + col] = val;
      }
    }
  }
}

// ---------------------------------------------------------------- RoPE split
__global__ void __launch_bounds__(256) k_rope(const float* __restrict__ qk,
    const float* __restrict__ cs, const float* __restrict__ sn,
    float* __restrict__ q, float* __restrict__ k){
  int idx = blockIdx.x*256 + threadIdx.x;
  int c = idx & 63;
  int h = (idx>>6) & 7;
  int p = (idx>>9) & 1;
  int n = (idx>>10) & 127;
  int bb = idx>>17;
  float t = qk[idx];
  float t2 = qk[(c<32) ? idx+32 : idx-32];
  if (c<32) t2 = -t2;
  float val = t*cs[n*64+c] + t2*sn[n*64+c];
  float* dst = p ? k : q;
  dst[(((size_t)bb*NH + h)*128 + n)*64 + c] = val;
}

// ---------------------------------------------------------------- attention matrix (bf16 out)
__global__ void __launch_bounds__(128) k_attn(const float* __restrict__ q,
    const float* __restrict__ k, bf16_t* __restrict__ attn){
  int i = blockIdx.x & 127;
  int bh = blockIdx.x >> 7;
  __shared__ float qs[64];
  __shared__ float sm[128];
  int tid = threadIdx.x;
  const float* qrow = q + ((size_t)bh*128 + i)*64;
  if (tid < 64) qs[tid] = qrow[tid];
  __syncthreads();
  const float* krow = k + ((size_t)bh*128 + tid)*64;
  float dot = 0.f;
  for (int c=0;c<64;c++) dot += qs[c]*krow[c];
  dot *= (1.0f/64.0f);
  sm[tid] = dot;
  __syncthreads();
  float mx = -1e30f;
  for (int j=0;j<128;j++) mx = fmaxf(mx, sm[j]);
  __syncthreads();
  float e = expf(dot - mx);
  sm[tid] = e;
  __syncthreads();
  float s = 0.f;
  for (int j=0;j<128;j++) s += sm[j];
  attn[(size_t)blockIdx.x*128 + tid] = f2b(e/s);
}

// ---------------------------------------------------------------- MFMA phi1: V-proj + y-attention
// block (bh, m=x): V[y][c] = un[b,y,m,:] @ Wv[:, h*64+c]  (K=256, MFMA)
//                  P1[i][c] = attnY[bh,i,:] @ V[:,c]      (K=128, MFMA)
// phi layout out: [bh][i][m][c]
#define AST 136   // 128 + 8 shorts
#define UST 72    // 64 + 8 shorts
#define VST 136
__global__ void __launch_bounds__(256) k_phi1m(const bf16_t* __restrict__ un,
    const short* __restrict__ WvP, const bf16_t* __restrict__ attn,
    bf16_t* __restrict__ phi){
  int m  = blockIdx.x & (NX-1);
  int bh = blockIdx.x >> 7;
  int b  = bh >> 3, h = bh & 7;
  __shared__ __align__(16) short At[128*AST];   // 34.8 KB
  __shared__ __align__(16) short unc[128*UST];  // 18.4 KB
  __shared__ __align__(16) short Vt[64*VST];    // 17.4 KB  [c][y]
  int tid = threadIdx.x;
  int lane = tid & 63, w = tid >> 6;
  int am = lane & 15, aq = lane >> 4;

  // stage attn slice (bh): 128x128 bf16 -> At (read only in phase 2)
  {
    const ushort* ag = (const ushort*)attn + (size_t)bh*16384;
    #pragma unroll
    for (int it=0; it<16; it++){
      int q = tid + it*256;          // < 4096 ushort4
      int i = q >> 5, j4 = q & 31;
      *(ushort4*)&At[i*AST + j4*4] = *(const ushort4*)(ag + i*128 + j4*4);
    }
  }

  // ---- phase 1: V-projection (wave w owns y rows w*32..+31, all 64 c)
  f32x4 v[2][4];
  #pragma unroll
  for (int mt=0;mt<2;mt++)
    #pragma unroll
    for (int nt=0;nt<4;nt++) v[mt][nt] = (f32x4){0.f,0.f,0.f,0.f};
  const ushort* ug = (const ushort*)un;
  for (int kc=0; kc<4; kc++){
    #pragma unroll
    for (int it=0; it<8; it++){
      int q = tid + it*256;          // < 2048 ushort4
      int y = q >> 4, c4 = q & 15;
      *(ushort4*)&unc[y*UST + c4*4] =
          *(const ushort4*)(ug + (((size_t)b*NY + y)*NX + m)*DIM + kc*64 + c4*4);
    }
    __syncthreads();
    #pragma unroll
    for (int kb=0; kb<2; kb++){
      short8 a2[2], bb[4];
      #pragma unroll
      for (int mt=0;mt<2;mt++)
        a2[mt] = *(const short8*)&unc[(w*32 + mt*16 + am)*UST + kb*32 + aq*8];
      int kbg = kc*2 + kb;           // of 8
      #pragma unroll
      for (int nt=0;nt<4;nt++)
        bb[nt] = *(const short8*)&WvP[(size_t)((kbg*32 + (h*4+nt))*64 + lane)*8];
      #pragma unroll
      for (int mt=0;mt<2;mt++)
        #pragma unroll
        for (int nt=0;nt<4;nt++)
          v[mt][nt] = __builtin_amdgcn_mfma_f32_16x16x32_bf16(a2[mt], bb[nt], v[mt][nt], 0,0,0);
    }
    __syncthreads();
  }
  // V frags -> Vt transposed [c][y] (4 consecutive y per frag -> ushort4)
  #pragma unroll
  for (int mt=0;mt<2;mt++)
    #pragma unroll
    for (int nt=0;nt<4;nt++){
      int c = nt*16 + am;
      int y0 = w*32 + mt*16 + aq*4;
      ushort4 pk;
      pk.x = (ushort)f2s(v[mt][nt][0]);
      pk.y = (ushort)f2s(v[mt][nt][1]);
      pk.z = (ushort)f2s(v[mt][nt][2]);
      pk.w = (ushort)f2s(v[mt][nt][3]);
      *(ushort4*)&Vt[c*VST + y0] = pk;
    }
  __syncthreads();

  // ---- phase 2: P1 = attnY @ V (rows i = w*32..+31, cols 64 c, K=128)
  f32x4 o[2][4];
  #pragma unroll
  for (int mt=0;mt<2;mt++)
    #pragma unroll
    for (int nt=0;nt<4;nt++) o[mt][nt] = (f32x4){0.f,0.f,0.f,0.f};
  #pragma unroll
  for (int kb=0; kb<4; kb++){
    short8 a2[2], bb[4];
    #pragma unroll
    for (int mt=0;mt<2;mt++)
      a2[mt] = *(const short8*)&At[(w*32 + mt*16 + am)*AST + kb*32 + aq*8];
    #pragma unroll
    for (int nt=0;nt<4;nt++)
      bb[nt] = *(const short8*)&Vt[(nt*16 + am)*VST + kb*32 + aq*8];
    #pragma unroll
    for (int mt=0;mt<2;mt++)
      #pragma unroll
      for (int nt=0;nt<4;nt++)
        o[mt][nt] = __builtin_amdgcn_mfma_f32_16x16x32_bf16(a2[mt], bb[nt], o[mt][nt], 0,0,0);
  }
  // write P1 -> phi[bh][i][m][c]
  ushort* pg = (ushort*)phi + (size_t)bh*NY*NX*DH_ + (size_t)m*DH_;
  #pragma unroll
  for (int mt=0;mt<2;mt++)
    #pragma unroll
    for (int nt=0;nt<4;nt++)
      #pragma unroll
      for (int reg=0;reg<4;reg++){
        int i = w*32 + mt*16 + aq*4 + reg;
        int c = nt*16 + am;
        pg[(size_t)i*(NX*DH_) + c] = (ushort)f2s(o[mt][nt][reg]);
      }
}

// ---------------------------------------------------------------- MFMA phi2: x-attention, in place
// block (bh, i): P2[l][c] = attnX[bh,l,:] @ P1[i,:,c]; slice [m][c] -> Pt[c][m]
__global__ void __launch_bounds__(256) k_phi2m(const bf16_t* __restrict__ attn,
    bf16_t* __restrict__ phi){
  int i  = blockIdx.x & (NY-1);
  int bh = blockIdx.x >> 7;
  __shared__ __align__(16) short Ax[128*AST];   // 34.8 KB
  __shared__ __align__(16) short Pt[64*VST];    // 17.4 KB  [c][m]
  int tid = threadIdx.x;
  int lane = tid & 63, w = tid >> 6;
  int am = lane & 15, aq = lane >> 4;

  {
    const ushort* ag = (const ushort*)attn + (size_t)bh*16384;
    #pragma unroll
    for (int it=0; it<16; it++){
      int q = tid + it*256;
      int r = q >> 5, j4 = q & 31;
      *(ushort4*)&Ax[r*AST + j4*4] = *(const ushort4*)(ag + r*128 + j4*4);
    }
  }
  ushort* pg = (ushort*)phi + (size_t)(bh*NY + i)*(NX*DH_);
  // slice is 128x64 shorts = 2048 ushort4 -> 8 iterations
  #pragma unroll
  for (int it=0; it<8; it++){
    int q = tid + it*256;            // < 2048 ushort4
    int mm = q >> 4, c4 = q & 15;    // mm in [0,128), c4 in [0,16)
    ushort4 v4 = *(const ushort4*)(pg + mm*DH_ + c4*4);
    Pt[(c4*4+0)*VST + mm] = v4.x;
    Pt[(c4*4+1)*VST + mm] = v4.y;
    Pt[(c4*4+2)*VST + mm] = v4.z;
    Pt[(c4*4+3)*VST + mm] = v4.w;
  }
  __syncthreads();

  f32x4 o[2][4];
  #pragma unroll
  for (int mt=0;mt<2;mt++)
    #pragma unroll
    for (int nt=0;nt<4;nt++) o[mt][nt] = (f32x4){0.f,0.f,0.f,0.f};
  #pragma unroll
  for (int kb=0; kb<4; kb++){
    short8 a2[2], bb[4];
    #pragma unroll
    for (int mt=0;mt<2;mt++)
      a2[mt] = *(const short8*)&Ax[(w*32 + mt*16 + am)*AST + kb*32 + aq*8];
    #pragma unroll
    for (int nt=0;nt<4;nt++)
      bb[nt] = *(const short8*)&Pt[(nt*16 + am)*VST + kb*32 + aq*8];
    #pragma unroll
    for (int mt=0;mt<2;mt++)
      #pragma unroll
      for (int nt=0;nt<4;nt++)
        o[mt][nt] = __builtin_amdgcn_mfma_f32_16x16x32_bf16(a2[mt], bb[nt], o[mt][nt], 0,0,0);
  }
  // write P2 in place: phi[bh][i][l][c]
  #pragma unroll
  for (int mt=0;mt<2;mt++)
    #pragma unroll
    for (int nt=0;nt<4;nt++)
      #pragma unroll
      for (int reg=0;reg<4;reg++){
        int l = w*32 + mt*16 + aq*4 + reg;
        int c = nt*16 + am;
        pg[(size_t)l*DH_ + c] = (ushort)f2s(o[mt][nt][reg]);
      }
}

// ---------------------------------------------------------------- GroupNorm + Wm + residual (MFMA)
// 32 rows/block (was 64): LDS 35.3 KB -> 4 blocks/CU for latency hiding.
#define GN_STRIDE 520
__global__ void __launch_bounds__(256) k_gn_wm(const bf16_t* __restrict__ phi,
    const short* __restrict__ WmP, const float* __restrict__ bm,
    const float* __restrict__ u, float* __restrict__ u2){
  __shared__ __align__(16) short X[32*GN_STRIDE];   // 33.3 KB
  __shared__ float mean_s[256], rstd_s[256];
  int tid = threadIdx.x;
  int lane = tid & 63, w = tid >> 6;
  size_t p0 = (size_t)blockIdx.x*32;
  int b  = (int)(p0 >> 14);
  int y  = (int)((p0 >> 7) & 127);
  int x0 = (int)(p0 & 127);

  #pragma unroll
  for (int it=0; it<16; it++){
    int q = tid + it*256;            // < 4096 ushort4 (32 rows x 512 f)
    int r = q >> 7, f4 = q & 127;
    int h = f4 >> 4, c4 = f4 & 15;
    const ushort* src = (const ushort*)phi +
        ((((size_t)b*NH + h)*NY + y)*NX + (x0 + r))*DH_ + c4*4;
    *(ushort4*)&X[r*GN_STRIDE + f4*4] = *(const ushort4*)src;
  }
  __syncthreads();
  {
    int g = tid;                     // 32 rows x 8 heads = 256 groups, 1/thread
    int r = g >> 3, h = g & 7;
    const short* base = &X[r*GN_STRIDE + h*64];
    float s=0.f, ss=0.f;
    #pragma unroll
    for (int i=0;i<16;i++){
      ushort4 v4 = *(const ushort4*)&base[i*4];
      float a = s2f((short)v4.x), bq = s2f((short)v4.y), cq = s2f((short)v4.z), d = s2f((short)v4.w);
      s += a+bq+cq+d; ss += a*a+bq*bq+cq*cq+d*d;
    }
    float mm = s*(1.0f/64.0f);
    float vv = ss*(1.0f/64.0f) - mm*mm;
    mean_s[g] = mm;
    rstd_s[g] = rsqrtf(vv + 1e-6f);
  }
  __syncthreads();
  #pragma unroll
  for (int it=0; it<16; it++){
    int q = tid + it*256;
    int r = q >> 7, f4 = q & 127;
    int h = f4 >> 4;
    float mm = mean_s[r*8 + h], rs = rstd_s[r*8 + h];
    short* ptr = &X[r*GN_STRIDE + f4*4];
    ushort4 v4 = *(ushort4*)ptr;
    v4.x = (ushort)f2s((s2f((short)v4.x)-mm)*rs);
    v4.y = (ushort)f2s((s2f((short)v4.y)-mm)*rs);
    v4.z = (ushort)f2s((s2f((short)v4.z)-mm)*rs);
    v4.w = (ushort)f2s((s2f((short)v4.w)-mm)*rs);
    *(ushort4*)ptr = v4;
  }
  __syncthreads();

  f32x4 o[2][4];
  #pragma unroll
  for (int mt=0;mt<2;mt++)
    #pragma unroll
    for (int nt=0;nt<4;nt++) o[mt][nt] = (f32x4){0.f,0.f,0.f,0.f};
  int am = lane & 15, aq = lane >> 4;
  for (int kb=0; kb<16; kb++){
    short8 a[2], bfr[4];
    #pragma unroll
    for (int mt=0;mt<2;mt++)
      a[mt] = *(const short8*)&X[(mt*16 + am)*GN_STRIDE + kb*32 + aq*8];
    #pragma unroll
    for (int nt=0;nt<4;nt++)
      bfr[nt] = *(const short8*)&WmP[(size_t)((kb*16 + (w*4+nt))*64 + lane)*8];
    #pragma unroll
    for (int mt=0;mt<2;mt++)
      #pragma unroll
      for (int nt=0;nt<4;nt++)
        o[mt][nt] = __builtin_amdgcn_mfma_f32_16x16x32_bf16(a[mt], bfr[nt], o[mt][nt], 0,0,0);
  }
  #pragma unroll
  for (int nt=0;nt<4;nt++){
    int col = w*64 + nt*16 + am;
    float bmv = bm[col];
    #pragma unroll
    for (int mt=0;mt<2;mt++){
      #pragma unroll
      for (int reg=0;reg<4;reg++){
        size_t p = p0 + mt*16 + aq*4 + reg;
        u2[p*DIM + col] = o[mt][nt][reg] + bmv + u[p*DIM + col];
      }
    }
  }
}

// ---------------------------------------------------------------- LN2 + MLP + residual (MFMA, in-place in d_out)
// 32 rows/block (was 64): LDS 33.8 KB -> 4 blocks/CU; acc regs halved.
#define ML_STRIDE 264
__global__ void __launch_bounds__(256) k_mlp_out(float* u2,
    const float* __restrict__ g2, const float* __restrict__ b2,
    const short* __restrict__ Wf1P, const float* __restrict__ bf1,
    const short* __restrict__ Wf2P, const float* __restrict__ bf2){
  __shared__ __align__(16) short X[32*ML_STRIDE];   // 16.9 KB
  __shared__ __align__(16) short H[32*ML_STRIDE];   // 16.9 KB
  int tid = threadIdx.x;
  int lane = tid & 63, w = tid >> 6;
  size_t p0 = (size_t)blockIdx.x*32;

  float4 g4 = *(const float4*)&g2[lane*4];
  float4 bq4 = *(const float4*)&b2[lane*4];
  for (int rr=0; rr<8; rr++){
    int r = w*8 + rr;
    float4 v = *(const float4*)&u2[(p0 + r)*DIM + lane*4];
    float s = v.x+v.y+v.z+v.w;
    float ss = v.x*v.x+v.y*v.y+v.z*v.z+v.w*v.w;
    #pragma unroll
    for (int off=32;off>0;off>>=1){ s += __shfl_down(s,off,64); ss += __shfl_down(ss,off,64); }
    s = __shfl(s,0,64); ss = __shfl(ss,0,64);
    float m = s*(1.0f/DIM);
    float rstd = rsqrtf(ss*(1.0f/DIM) - m*m + 1e-5f);
    ushort4 xo;
    xo.x = (ushort)f2s((v.x-m)*rstd*g4.x + bq4.x);
    xo.y = (ushort)f2s((v.y-m)*rstd*g4.y + bq4.y);
    xo.z = (ushort)f2s((v.z-m)*rstd*g4.z + bq4.z);
    xo.w = (ushort)f2s((v.w-m)*rstd*g4.w + bq4.w);
    *(ushort4*)&X[r*ML_STRIDE + lane*4] = xo;
  }
  __syncthreads();

  int am = lane & 15, aq = lane >> 4;
  f32x4 o[2][4];
  #pragma unroll
  for (int mt=0;mt<2;mt++)
    #pragma unroll
    for (int nt=0;nt<4;nt++) o[mt][nt] = (f32x4){0.f,0.f,0.f,0.f};

  for (int nc=0; nc<4; nc++){
    f32x4 hacc[2][4];
    #pragma unroll
    for (int mt=0;mt<2;mt++)
      #pragma unroll
      for (int nt=0;nt<4;nt++) hacc[mt][nt] = (f32x4){0.f,0.f,0.f,0.f};
    for (int kb=0; kb<8; kb++){
      short8 a[2], bfr[4];
      #pragma unroll
      for (int mt=0;mt<2;mt++)
        a[mt] = *(const short8*)&X[(mt*16 + am)*ML_STRIDE + kb*32 + aq*8];
      #pragma unroll
      for (int nt=0;nt<4;nt++){
        int ntg = nc*16 + w*4 + nt;
        bfr[nt] = *(const short8*)&Wf1P[(size_t)((kb*64 + ntg)*64 + lane)*8];
      }
      #pragma unroll
      for (int mt=0;mt<2;mt++)
        #pragma unroll
        for (int nt=0;nt<4;nt++)
          hacc[mt][nt] = __builtin_amdgcn_mfma_f32_16x16x32_bf16(a[mt], bfr[nt], hacc[mt][nt], 0,0,0);
    }
    #pragma unroll
    for (int nt=0;nt<4;nt++){
      int col_l = w*64 + nt*16 + am;
      float bv = bf1[nc*256 + col_l];
      #pragma unroll
      for (int mt=0;mt<2;mt++){
        #pragma unroll
        for (int reg=0;reg<4;reg++){
          int row = mt*16 + aq*4 + reg;
          H[row*ML_STRIDE + col_l] = f2s(gelu_tanh(hacc[mt][nt][reg] + bv));
        }
      }
    }
    __syncthreads();
    for (int kb=0; kb<8; kb++){
      short8 a[2], bfr[4];
      #pragma unroll
      for (int mt=0;mt<2;mt++)
        a[mt] = *(const short8*)&H[(mt*16 + am)*ML_STRIDE + kb*32 + aq*8];
      int kbg = nc*8 + kb;
      #pragma unroll
      for (int nt=0;nt<4;nt++)
        bfr[nt] = *(const short8*)&Wf2P[(size_t)((kbg*16 + (w*4+nt))*64 + lane)*8];
      #pragma unroll
      for (int mt=0;mt<2;mt++)
        #pragma unroll
        for (int nt=0;nt<4;nt++)
          o[mt][nt] = __builtin_amdgcn_mfma_f32_16x16x32_bf16(a[mt], bfr[nt], o[mt][nt], 0,0,0);
    }
    __syncthreads();
  }

  #pragma unroll
  for (int nt=0;nt<4;nt++){
    int col = w*64 + nt*16 + am;
    float bv = bf2[col];
    #pragma unroll
    for (int mt=0;mt<2;mt++){
      #pragma unroll
      for (int reg=0;reg<4;reg++){
        size_t p = p0 + mt*16 + aq*4 + reg;
        float res = u2[p*DIM + col];
        u2[p*DIM + col] = o[mt][nt][reg] + bv + res;
      }
    }
  }
}

extern "C" void kernel_launch(void* const* d_in, const int* in_sizes, int n_in,
                              void* d_out, int out_size, void* d_ws, size_t ws_size,
                              hipStream_t stream){
  const float* u    = (const float*)d_in[0];
  const float* rcy  = (const float*)d_in[1];
  const float* rsy  = (const float*)d_in[2];
  const float* rcx  = (const float*)d_in[3];
  const float* rsx  = (const float*)d_in[4];
  const float* ln1g = (const float*)d_in[6];
  const float* ln1b = (const float*)d_in[7];
  const float* ln2g = (const float*)d_in[8];
  const float* ln2b = (const float*)d_in[9];
  const float* Wv   = (const float*)d_in[10];
  const float* Wyin = (const float*)d_in[11];
  const float* Wy1  = (const float*)d_in[12];
  const float* by1  = (const float*)d_in[13];
  const float* Wy2  = (const float*)d_in[14];
  const float* by2  = (const float*)d_in[15];
  const float* Wxin = (const float*)d_in[16];
  const float* Wx1  = (const float*)d_in[17];
  const float* bx1  = (const float*)d_in[18];
  const float* Wx2  = (const float*)d_in[19];
  const float* bx2  = (const float*)d_in[20];
  const float* Wqkx = (const float*)d_in[21];
  const float* Wqky = (const float*)d_in[22];
  const float* Wm   = (const float*)d_in[23];
  const float* bm   = (const float*)d_in[24];
  const float* Wf1  = (const float*)d_in[25];
  const float* bf1  = (const float*)d_in[26];
  const float* Wf2  = (const float*)d_in[27];
  const float* bf2  = (const float*)d_in[28];

  char* w = (char*)d_ws;
  auto alloc = [&](size_t n) -> void* {
    void* p = (void*)w;
    w += (n + 255) & ~(size_t)255;
    return p;
  };
  bf16_t* UN   = (bf16_t*)alloc((size_t)NPOS*DIM*2);               // 32 MiB
  bf16_t* PHI  = (bf16_t*)alloc((size_t)NB*NH*NY*NX*DH_*2);        // 64 MiB
  float* POOLY = (float*)alloc((size_t)NB*NY*DIM*4);
  float* POOLX = (float*)alloc((size_t)NB*NX*DIM*4);
  float* TY    = (float*)alloc((size_t)512*256*4);
  float* TX    = (float*)alloc((size_t)512*256*4);
  float* HY    = (float*)alloc((size_t)512*1024*4);
  float* HX    = (float*)alloc((size_t)512*1024*4);
  float* UY    = (float*)alloc((size_t)512*256*4);
  float* UX    = (float*)alloc((size_t)512*256*4);
  float* QKY   = (float*)alloc((size_t)512*1024*4);
  float* QKX   = (float*)alloc((size_t)512*1024*4);
  float* QRY   = (float*)alloc((size_t)NB*NH*128*64*4);
  float* KRY   = (float*)alloc((size_t)NB*NH*128*64*4);
  float* QRX   = (float*)alloc((size_t)NB*NH*128*64*4);
  float* KRX   = (float*)alloc((size_t)NB*NH*128*64*4);
  bf16_t* ATTNY = (bf16_t*)alloc((size_t)NB*NH*128*128*2);
  bf16_t* ATTNX = (bf16_t*)alloc((size_t)NB*NH*128*128*2);
  short* WF1P  = (short*)alloc((size_t)256*1024*2);
  short* WF2P  = (short*)alloc((size_t)1024*256*2);
  short* WMP   = (short*)alloc((size_t)512*256*2);
  short* WVP   = (short*)alloc((size_t)256*512*2);
  short* WYINP = (short*)alloc((size_t)256*256*2);
  short* WY1P  = (short*)alloc((size_t)256*1024*2);
  short* WY2P  = (short*)alloc((size_t)1024*256*2);
  short* WQKYP = (short*)alloc((size_t)256*1024*2);
  short* WXINP = (short*)alloc((size_t)256*256*2);
  short* WX1P  = (short*)alloc((size_t)256*1024*2);
  short* WX2P  = (short*)alloc((size_t)1024*256*2);
  short* WQKXP = (short*)alloc((size_t)256*1024*2);
  float* U2 = (float*)d_out;
  (void)in_sizes; (void)n_in; (void)out_size; (void)ws_size;

  k_pack<<<(256*1024/8)/256, 256, 0, stream>>>(Wf1, WF1P, 256, 1024);
  k_pack<<<(1024*256/8)/256, 256, 0, stream>>>(Wf2, WF2P, 1024, 256);
  k_pack<<<(512*256/8)/256, 256, 0, stream>>>(Wm, WMP, 512, 256);
  k_pack<<<(256*512/8)/256, 256, 0, stream>>>(Wv, WVP, 256, 512);
  k_pack<<<(256*256/8)/256, 256, 0, stream>>>(Wyin, WYINP, 256, 256);
  k_pack<<<(256*1024/8)/256, 256, 0, stream>>>(Wy1, WY1P, 256, 1024);
  k_pack<<<(1024*256/8)/256, 256, 0, stream>>>(Wy2, WY2P, 1024, 256);
  k_pack<<<(256*1024/8)/256, 256, 0, stream>>>(Wqky, WQKYP, 256, 1024);
  k_pack<<<(256*256/8)/256, 256, 0, stream>>>(Wxin, WXINP, 256, 256);
  k_pack<<<(256*1024/8)/256, 256, 0, stream>>>(Wx1, WX1P, 256, 1024);
  k_pack<<<(1024*256/8)/256, 256, 0, stream>>>(Wx2, WX2P, 1024, 256);
  k_pack<<<(256*1024/8)/256, 256, 0, stream>>>(Wqkx, WQKXP, 256, 1024);

  k_ln1<<<NPOS/4, 256, 0, stream>>>(u, ln1g, ln1b, UN);
  k_pool_y<<<NB*NY, 256, 0, stream>>>(UN, POOLY);
  k_pool_x<<<NB*NX, 256, 0, stream>>>(UN, POOLX);

  // y chain: pool -> Win -> gelu-MLP -> QK   (M=512 rows, MFMA)
  k_gemm_mfma<<<dim3(8,1), 256, 0, stream>>>(POOLY, WYINP, (const float*)nullptr, TY, 256, 256, 0);
  k_gemm_mfma<<<dim3(8,4), 256, 0, stream>>>(TY, WY1P, by1, HY, 1024, 256, 1);
  k_gemm_mfma<<<dim3(8,1), 256, 0, stream>>>(HY, WY2P, by2, UY, 256, 1024, 0);
  k_gemm_mfma<<<dim3(8,4), 256, 0, stream>>>(UY, WQKYP, (const float*)nullptr, QKY, 1024, 256, 0);
  // x chain
  k_gemm_mfma<<<dim3(8,1), 256, 0, stream>>>(POOLX, WXINP, (const float*)nullptr, TX, 256, 256, 0);
  k_gemm_mfma<<<dim3(8,4), 256, 0, stream>>>(TX, WX1P, bx1, HX, 1024, 256, 1);
  k_gemm_mfma<<<dim3(8,1), 256, 0, stream>>>(HX, WX2P, bx2, UX, 256, 1024, 0);
  k_gemm_mfma<<<dim3(8,4), 256, 0, stream>>>(UX, WQKXP, (const float*)nullptr, QKX, 1024, 256, 0);

  k_rope<<<(NB*128*1024)/256, 256, 0, stream>>>(QKY, rcy, rsy, QRY, KRY);
  k_rope<<<(NB*128*1024)/256, 256, 0, stream>>>(QKX, rcx, rsx, QRX, KRX);
  k_attn<<<NB*NH*128, 128, 0, stream>>>(QRY, KRY, ATTNY);
  k_attn<<<NB*NH*128, 128, 0, stream>>>(QRX, KRX, ATTNX);
  k_phi1m<<<NB*NH*NX, 256, 0, stream>>>(UN, WVP, ATTNY, PHI);
  k_phi2m<<<NB*NH*NY, 256, 0, stream>>>(ATTNX, PHI);
  k_gn_wm<<<NPOS/32, 256, 0, stream>>>(PHI, WMP, bm, u, U2);
  k_mlp_out<<<NPOS/32, 256, 0, stream>>>(U2, ln2g, ln2b, WF1P, bf1, WF2P, bf2);
}

// Round 4
// 679.169 us; speedup vs baseline: 2.9696x; 1.0487x over previous
//
#include <hip/hip_runtime.h>
#include <hip/hip_bf16.h>
#include <math.h>

// Problem constants (B=4, 128x128 grid, DIM=256, 8 heads x 64)
#define NB 4
#define NY 128
#define NX 128
#define DIM 256
#define NH 8
#define DH_ 64
#define HDIM 512   // NH*DH
#define HID 1024
#define NPOS (NB*NY*NX)   // 65536

typedef __hip_bfloat16 bf16_t;
typedef __attribute__((ext_vector_type(8))) short short8;   // 8 bf16 = 1 MFMA A/B frag
typedef __attribute__((ext_vector_type(4))) float f32x4;    // MFMA C/D frag

__device__ __forceinline__ float b2f(bf16_t x){ return __bfloat162float(x); }
__device__ __forceinline__ bf16_t f2b(float x){ return __float2bfloat16(x); }
__device__ __forceinline__ short f2s(float x){ bf16_t h = __float2bfloat16(x); return *reinterpret_cast<short*>(&h); }
__device__ __forceinline__ float s2f(short x){ bf16_t h = *reinterpret_cast<bf16_t*>(&x); return __bfloat162float(h); }

// MFMA fragment layout (gfx950, verified in-round 3->4):
//  A[m][k]: m = lane&15, k = (lane>>4)*8 + j
//  B[k][n]: n = lane&15, k = (lane>>4)*8 + j
//  D[row][col]: col = lane&15, row = (lane>>4)*4 + reg

// gelu tanh-approx: 0.5x(1+tanh(t)) == x*sigmoid(2t); __expf maps to v_exp_f32.
__device__ __forceinline__ float gelu_tanh(float x){
  float z = 1.5957691216057308f*(x + 0.044715f*x*x*x);   // 2*0.79788456*(x+0.044715x^3)
  return x / (1.0f + __expf(-z));
}

// ---------------------------------------------------------------- weight pack
// W[K x N] f32 row-major -> bf16 B-fragment order
__global__ void __launch_bounds__(256) k_pack(const float* __restrict__ W,
    short* __restrict__ out, int K, int N){
  int tid = blockIdx.x*256 + threadIdx.x;      // < K*N/8
  int lane = tid & 63;
  int rem = tid >> 6;
  int ntiles = N >> 4;
  int nt = rem % ntiles, kb = rem / ntiles;
  int n = nt*16 + (lane & 15);
  int k0 = kb*32 + (lane>>4)*8;
  short8 v;
  #pragma unroll
  for (int j=0;j<8;j++) v[j] = f2s(W[(size_t)(k0+j)*N + n]);
  *(short8*)&out[(size_t)tid*8] = v;
}

// ---------------------------------------------------------------- LN1 (f32 in -> bf16 un)
__global__ void __launch_bounds__(256) k_ln1(const float* __restrict__ u,
    const float* __restrict__ g, const float* __restrict__ b,
    bf16_t* __restrict__ un){
  int wave = threadIdx.x >> 6, lane = threadIdx.x & 63;
  size_t row = (size_t)blockIdx.x*4 + wave;
  const float* x = u + row*DIM;
  float v[4]; float s=0.f, ss=0.f;
  #pragma unroll
  for (int j=0;j<4;j++){ float t = x[lane + j*64]; v[j]=t; s+=t; ss+=t*t; }
  #pragma unroll
  for (int off=32;off>0;off>>=1){ s += __shfl_down(s,off,64); ss += __shfl_down(ss,off,64); }
  s = __shfl(s,0,64); ss = __shfl(ss,0,64);
  float m = s*(1.0f/DIM);
  float var = ss*(1.0f/DIM) - m*m;
  float r = rsqrtf(var + 1e-5f);
  bf16_t* o = un + row*DIM;
  #pragma unroll
  for (int j=0;j<4;j++){
    int f = lane + j*64;
    o[f] = f2b((v[j]-m)*r*g[f] + b[f]);
  }
}

// ---------------------------------------------------------------- pooling (bf16 un -> f32)
__global__ void __launch_bounds__(256) k_pool_y(const bf16_t* __restrict__ un, float* __restrict__ pooly){
  int by = blockIdx.x;
  int d = threadIdx.x;
  size_t base = (size_t)by*NX*DIM + d;
  float s = 0.f;
  for (int x=0;x<NX;x++) s += b2f(un[base + (size_t)x*DIM]);
  pooly[(size_t)by*DIM + d] = s*(1.0f/NX);
}
__global__ void __launch_bounds__(256) k_pool_x(const bf16_t* __restrict__ un, float* __restrict__ poolx){
  int bb = blockIdx.x / NX, x = blockIdx.x % NX;
  int d = threadIdx.x;
  size_t base = ((size_t)bb*NY*NX + x)*DIM + d;
  float s = 0.f;
  for (int y=0;y<NY;y++) s += b2f(un[base + (size_t)y*NX*DIM]);
  poolx[(size_t)blockIdx.x*DIM + d] = s*(1.0f/NY);
}

// ---------------------------------------------------------------- MFMA GEMM for the small chain
// C[M x N] = op(A[M x K] @ W + bias); A f32 (bf16-staged), W packed bf16 frags,
// f32 MFMA accumulate, f32 out. grid = (M/64, N/256), block 256.
#define GS_STRIDE 72
__global__ void __launch_bounds__(256) k_gemm_mfma(const float* __restrict__ A,
    const short* __restrict__ WP, const float* __restrict__ bias,
    float* __restrict__ C, int N, int K, int dogelu){
  __shared__ __align__(16) short As[64*GS_STRIDE];   // 9.2 KB
  int tid = threadIdx.x;
  int lane = tid & 63, w = tid >> 6;
  int am = lane & 15, aq = lane >> 4;
  int m0 = blockIdx.x*64;
  int nt0 = blockIdx.y*16;          // n-tile offset (16 tiles of 16 cols = 256 cols/block)
  int ntiles = N >> 4;
  f32x4 o[4][4];
  #pragma unroll
  for (int mt=0;mt<4;mt++)
    #pragma unroll
    for (int nt=0;nt<4;nt++) o[mt][nt] = (f32x4){0.f,0.f,0.f,0.f};

  for (int kc=0; kc<K; kc+=64){
    // stage A[m0..+64][kc..+64] f32 -> bf16 LDS (64x64, 1024 float4s, 4/thread)
    #pragma unroll
    for (int it=0; it<4; it++){
      int q = tid + it*256;
      int r = q >> 4, c4 = q & 15;
      float4 v = *(const float4*)&A[(size_t)(m0+r)*K + kc + c4*4];
      ushort4 p;
      p.x = (ushort)f2s(v.x); p.y = (ushort)f2s(v.y);
      p.z = (ushort)f2s(v.z); p.w = (ushort)f2s(v.w);
      *(ushort4*)&As[r*GS_STRIDE + c4*4] = p;
    }
    __syncthreads();
    #pragma unroll
    for (int kb=0; kb<2; kb++){
      short8 a[4], bfr[4];
      #pragma unroll
      for (int mt=0;mt<4;mt++)
        a[mt] = *(const short8*)&As[(mt*16+am)*GS_STRIDE + kb*32 + aq*8];
      int kbg = (kc>>5) + kb;
      #pragma unroll
      for (int nt=0;nt<4;nt++){
        int ntg = nt0 + w*4 + nt;
        bfr[nt] = *(const short8*)&WP[(size_t)((kbg*ntiles + ntg)*64 + lane)*8];
      }
      #pragma unroll
      for (int mt=0;mt<4;mt++)
        #pragma unroll
        for (int nt=0;nt<4;nt++)
          o[mt][nt] = __builtin_amdgcn_mfma_f32_16x16x32_bf16(a[mt], bfr[nt], o[mt][nt], 0,0,0);
    }
    __syncthreads();
  }

  #pragma unroll
  for (int nt=0;nt<4;nt++){
    int col = (nt0 + w*4 + nt)*16 + am;
    float bv = bias ? bias[col] : 0.f;
    #pragma unroll
    for (int mt=0;mt<4;mt++){
      #pragma unroll
      for (int reg=0;reg<4;reg++){
        int row = m0 + mt*16 + aq*4 + reg;
        float val = o[mt][nt][reg] + bv;
        if (dogelu) val = gelu_tanh(val);
        C[(size_t)row*N + col] = val;
      }
    }
  }
}

// ---------------------------------------------------------------- RoPE split
__global__ void __launch_bounds__(256) k_rope(const float* __restrict__ qk,
    const float* __restrict__ cs, const float* __restrict__ sn,
    float* __restrict__ q, float* __restrict__ k){
  int idx = blockIdx.x*256 + threadIdx.x;
  int c = idx & 63;
  int h = (idx>>6) & 7;
  int p = (idx>>9) & 1;
  int n = (idx>>10) & 127;
  int bb = idx>>17;
  float t = qk[idx];
  float t2 = qk[(c<32) ? idx+32 : idx-32];
  if (c<32) t2 = -t2;
  float val = t*cs[n*64+c] + t2*sn[n*64+c];
  float* dst = p ? k : q;
  dst[(((size_t)bb*NH + h)*128 + n)*64 + c] = val;
}

// ---------------------------------------------------------------- attention matrix (bf16 out)
__global__ void __launch_bounds__(128) k_attn(const float* __restrict__ q,
    const float* __restrict__ k, bf16_t* __restrict__ attn){
  int i = blockIdx.x & 127;
  int bh = blockIdx.x >> 7;
  __shared__ float qs[64];
  __shared__ float sm[128];
  int tid = threadIdx.x;
  const float* qrow = q + ((size_t)bh*128 + i)*64;
  if (tid < 64) qs[tid] = qrow[tid];
  __syncthreads();
  const float* krow = k + ((size_t)bh*128 + tid)*64;
  float dot = 0.f;
  for (int c=0;c<64;c++) dot += qs[c]*krow[c];
  dot *= (1.0f/64.0f);
  sm[tid] = dot;
  __syncthreads();
  float mx = -1e30f;
  for (int j=0;j<128;j++) mx = fmaxf(mx, sm[j]);
  __syncthreads();
  float e = expf(dot - mx);
  sm[tid] = e;
  __syncthreads();
  float s = 0.f;
  for (int j=0;j<128;j++) s += sm[j];
  attn[(size_t)blockIdx.x*128 + tid] = f2b(e/s);
}

// ---------------------------------------------------------------- MFMA phi1: V-proj + y-attention
// block (bh, m=x): V[y][c] = un[b,y,m,:] @ Wv[:, h*64+c]  (K=256, MFMA)
//                  P1[i][c] = attnY[bh,i,:] @ V[:,c]      (K=128, MFMA)
// phi layout out: [bh][i][m][c]
#define AST 136   // 128 + 8 shorts
#define UST 72    // 64 + 8 shorts
#define VST 136
__global__ void __launch_bounds__(256) k_phi1m(const bf16_t* __restrict__ un,
    const short* __restrict__ WvP, const bf16_t* __restrict__ attn,
    bf16_t* __restrict__ phi){
  int m  = blockIdx.x & (NX-1);
  int bh = blockIdx.x >> 7;
  int b  = bh >> 3, h = bh & 7;
  __shared__ __align__(16) short At[128*AST];   // 34.8 KB
  __shared__ __align__(16) short unc[128*UST];  // 18.4 KB
  __shared__ __align__(16) short Vt[64*VST];    // 17.4 KB  [c][y]
  int tid = threadIdx.x;
  int lane = tid & 63, w = tid >> 6;
  int am = lane & 15, aq = lane >> 4;

  // stage attn slice (bh): 128x128 bf16 -> At (read only in phase 2)
  {
    const ushort* ag = (const ushort*)attn + (size_t)bh*16384;
    #pragma unroll
    for (int it=0; it<16; it++){
      int q = tid + it*256;          // < 4096 ushort4
      int i = q >> 5, j4 = q & 31;
      *(ushort4*)&At[i*AST + j4*4] = *(const ushort4*)(ag + i*128 + j4*4);
    }
  }

  // ---- phase 1: V-projection (wave w owns y rows w*32..+31, all 64 c)
  f32x4 v[2][4];
  #pragma unroll
  for (int mt=0;mt<2;mt++)
    #pragma unroll
    for (int nt=0;nt<4;nt++) v[mt][nt] = (f32x4){0.f,0.f,0.f,0.f};
  const ushort* ug = (const ushort*)un;
  for (int kc=0; kc<4; kc++){
    #pragma unroll
    for (int it=0; it<8; it++){
      int q = tid + it*256;          // < 2048 ushort4
      int y = q >> 4, c4 = q & 15;
      *(ushort4*)&unc[y*UST + c4*4] =
          *(const ushort4*)(ug + (((size_t)b*NY + y)*NX + m)*DIM + kc*64 + c4*4);
    }
    __syncthreads();
    #pragma unroll
    for (int kb=0; kb<2; kb++){
      short8 a2[2], bb[4];
      #pragma unroll
      for (int mt=0;mt<2;mt++)
        a2[mt] = *(const short8*)&unc[(w*32 + mt*16 + am)*UST + kb*32 + aq*8];
      int kbg = kc*2 + kb;           // of 8
      #pragma unroll
      for (int nt=0;nt<4;nt++)
        bb[nt] = *(const short8*)&WvP[(size_t)((kbg*32 + (h*4+nt))*64 + lane)*8];
      #pragma unroll
      for (int mt=0;mt<2;mt++)
        #pragma unroll
        for (int nt=0;nt<4;nt++)
          v[mt][nt] = __builtin_amdgcn_mfma_f32_16x16x32_bf16(a2[mt], bb[nt], v[mt][nt], 0,0,0);
    }
    __syncthreads();
  }
  // V frags -> Vt transposed [c][y] (4 consecutive y per frag -> ushort4)
  #pragma unroll
  for (int mt=0;mt<2;mt++)
    #pragma unroll
    for (int nt=0;nt<4;nt++){
      int c = nt*16 + am;
      int y0 = w*32 + mt*16 + aq*4;
      ushort4 pk;
      pk.x = (ushort)f2s(v[mt][nt][0]);
      pk.y = (ushort)f2s(v[mt][nt][1]);
      pk.z = (ushort)f2s(v[mt][nt][2]);
      pk.w = (ushort)f2s(v[mt][nt][3]);
      *(ushort4*)&Vt[c*VST + y0] = pk;
    }
  __syncthreads();

  // ---- phase 2: P1 = attnY @ V (rows i = w*32..+31, cols 64 c, K=128)
  f32x4 o[2][4];
  #pragma unroll
  for (int mt=0;mt<2;mt++)
    #pragma unroll
    for (int nt=0;nt<4;nt++) o[mt][nt] = (f32x4){0.f,0.f,0.f,0.f};
  #pragma unroll
  for (int kb=0; kb<4; kb++){
    short8 a2[2], bb[4];
    #pragma unroll
    for (int mt=0;mt<2;mt++)
      a2[mt] = *(const short8*)&At[(w*32 + mt*16 + am)*AST + kb*32 + aq*8];
    #pragma unroll
    for (int nt=0;nt<4;nt++)
      bb[nt] = *(const short8*)&Vt[(nt*16 + am)*VST + kb*32 + aq*8];
    #pragma unroll
    for (int mt=0;mt<2;mt++)
      #pragma unroll
      for (int nt=0;nt<4;nt++)
        o[mt][nt] = __builtin_amdgcn_mfma_f32_16x16x32_bf16(a2[mt], bb[nt], o[mt][nt], 0,0,0);
  }
  // write P1 -> phi[bh][i][m][c]
  ushort* pg = (ushort*)phi + (size_t)bh*NY*NX*DH_ + (size_t)m*DH_;
  #pragma unroll
  for (int mt=0;mt<2;mt++)
    #pragma unroll
    for (int nt=0;nt<4;nt++)
      #pragma unroll
      for (int reg=0;reg<4;reg++){
        int i = w*32 + mt*16 + aq*4 + reg;
        int c = nt*16 + am;
        pg[(size_t)i*(NX*DH_) + c] = (ushort)f2s(o[mt][nt][reg]);
      }
}

// ---------------------------------------------------------------- MFMA phi2: x-attention, in place
// block (bh, i): P2[l][c] = attnX[bh,l,:] @ P1[i,:,c]; slice [m][c] -> Pt[c][m]
__global__ void __launch_bounds__(256) k_phi2m(const bf16_t* __restrict__ attn,
    bf16_t* __restrict__ phi){
  int i  = blockIdx.x & (NY-1);
  int bh = blockIdx.x >> 7;
  __shared__ __align__(16) short Ax[128*AST];   // 34.8 KB
  __shared__ __align__(16) short Pt[64*VST];    // 17.4 KB  [c][m]
  int tid = threadIdx.x;
  int lane = tid & 63, w = tid >> 6;
  int am = lane & 15, aq = lane >> 4;

  {
    const ushort* ag = (const ushort*)attn + (size_t)bh*16384;
    #pragma unroll
    for (int it=0; it<16; it++){
      int q = tid + it*256;
      int r = q >> 5, j4 = q & 31;
      *(ushort4*)&Ax[r*AST + j4*4] = *(const ushort4*)(ag + r*128 + j4*4);
    }
  }
  ushort* pg = (ushort*)phi + (size_t)(bh*NY + i)*(NX*DH_);
  // slice is 128x64 shorts = 2048 ushort4 -> 8 iterations
  #pragma unroll
  for (int it=0; it<8; it++){
    int q = tid + it*256;            // < 2048 ushort4
    int mm = q >> 4, c4 = q & 15;    // mm in [0,128), c4 in [0,16)
    ushort4 v4 = *(const ushort4*)(pg + mm*DH_ + c4*4);
    Pt[(c4*4+0)*VST + mm] = v4.x;
    Pt[(c4*4+1)*VST + mm] = v4.y;
    Pt[(c4*4+2)*VST + mm] = v4.z;
    Pt[(c4*4+3)*VST + mm] = v4.w;
  }
  __syncthreads();

  f32x4 o[2][4];
  #pragma unroll
  for (int mt=0;mt<2;mt++)
    #pragma unroll
    for (int nt=0;nt<4;nt++) o[mt][nt] = (f32x4){0.f,0.f,0.f,0.f};
  #pragma unroll
  for (int kb=0; kb<4; kb++){
    short8 a2[2], bb[4];
    #pragma unroll
    for (int mt=0;mt<2;mt++)
      a2[mt] = *(const short8*)&Ax[(w*32 + mt*16 + am)*AST + kb*32 + aq*8];
    #pragma unroll
    for (int nt=0;nt<4;nt++)
      bb[nt] = *(const short8*)&Pt[(nt*16 + am)*VST + kb*32 + aq*8];
    #pragma unroll
    for (int mt=0;mt<2;mt++)
      #pragma unroll
      for (int nt=0;nt<4;nt++)
        o[mt][nt] = __builtin_amdgcn_mfma_f32_16x16x32_bf16(a2[mt], bb[nt], o[mt][nt], 0,0,0);
  }
  // write P2 in place: phi[bh][i][l][c]
  #pragma unroll
  for (int mt=0;mt<2;mt++)
    #pragma unroll
    for (int nt=0;nt<4;nt++)
      #pragma unroll
      for (int reg=0;reg<4;reg++){
        int l = w*32 + mt*16 + aq*4 + reg;
        int c = nt*16 + am;
        pg[(size_t)l*DH_ + c] = (ushort)f2s(o[mt][nt][reg]);
      }
}

// ---------------------------------------------------------------- GroupNorm + Wm + residual (MFMA)
// 64 rows/block, 512 threads (8 waves = 2 row-halves x 4 col-quarters):
// row-halves share Wm fragments -> per-row L2 weight traffic halved vs 32-row.
#define GN_STRIDE 520
__global__ void __launch_bounds__(512) k_gn_wm(const bf16_t* __restrict__ phi,
    const short* __restrict__ WmP, const float* __restrict__ bm,
    const float* __restrict__ u, float* __restrict__ u2){
  __shared__ __align__(16) short X[64*GN_STRIDE];   // 66.6 KB
  __shared__ float mean_s[512], rstd_s[512];
  int tid = threadIdx.x;
  int lane = tid & 63, w = tid >> 6;
  int wh = w >> 2, wl = w & 3;
  size_t p0 = (size_t)blockIdx.x*64;
  int b  = (int)(p0 >> 14);
  int y  = (int)((p0 >> 7) & 127);
  int x0 = (int)(p0 & 127);

  #pragma unroll
  for (int it=0; it<16; it++){
    int q = tid + it*512;            // < 8192 ushort4 (64 rows x 512 f)
    int r = q >> 7, f4 = q & 127;
    int h = f4 >> 4, c4 = f4 & 15;
    const ushort* src = (const ushort*)phi +
        ((((size_t)b*NH + h)*NY + y)*NX + (x0 + r))*DH_ + c4*4;
    *(ushort4*)&X[r*GN_STRIDE + f4*4] = *(const ushort4*)src;
  }
  __syncthreads();
  {
    int g = tid;                     // 64 rows x 8 heads = 512 groups, 1/thread
    int r = g >> 3, h = g & 7;
    const short* base = &X[r*GN_STRIDE + h*64];
    float s=0.f, ss=0.f;
    #pragma unroll
    for (int i=0;i<16;i++){
      ushort4 v4 = *(const ushort4*)&base[i*4];
      float a = s2f((short)v4.x), bq = s2f((short)v4.y), cq = s2f((short)v4.z), d = s2f((short)v4.w);
      s += a+bq+cq+d; ss += a*a+bq*bq+cq*cq+d*d;
    }
    float mm = s*(1.0f/64.0f);
    float vv = ss*(1.0f/64.0f) - mm*mm;
    mean_s[g] = mm;
    rstd_s[g] = rsqrtf(vv + 1e-6f);
  }
  __syncthreads();
  #pragma unroll
  for (int it=0; it<16; it++){
    int q = tid + it*512;
    int r = q >> 7, f4 = q & 127;
    int h = f4 >> 4;
    float mm = mean_s[r*8 + h], rs = rstd_s[r*8 + h];
    short* ptr = &X[r*GN_STRIDE + f4*4];
    ushort4 v4 = *(ushort4*)ptr;
    v4.x = (ushort)f2s((s2f((short)v4.x)-mm)*rs);
    v4.y = (ushort)f2s((s2f((short)v4.y)-mm)*rs);
    v4.z = (ushort)f2s((s2f((short)v4.z)-mm)*rs);
    v4.w = (ushort)f2s((s2f((short)v4.w)-mm)*rs);
    *(ushort4*)ptr = v4;
  }
  __syncthreads();

  f32x4 o[2][4];
  #pragma unroll
  for (int mt=0;mt<2;mt++)
    #pragma unroll
    for (int nt=0;nt<4;nt++) o[mt][nt] = (f32x4){0.f,0.f,0.f,0.f};
  int am = lane & 15, aq = lane >> 4;
  for (int kb=0; kb<16; kb++){
    short8 a[2], bfr[4];
    #pragma unroll
    for (int mt=0;mt<2;mt++)
      a[mt] = *(const short8*)&X[(wh*32 + mt*16 + am)*GN_STRIDE + kb*32 + aq*8];
    #pragma unroll
    for (int nt=0;nt<4;nt++)
      bfr[nt] = *(const short8*)&WmP[(size_t)((kb*16 + (wl*4+nt))*64 + lane)*8];
    #pragma unroll
    for (int mt=0;mt<2;mt++)
      #pragma unroll
      for (int nt=0;nt<4;nt++)
        o[mt][nt] = __builtin_amdgcn_mfma_f32_16x16x32_bf16(a[mt], bfr[nt], o[mt][nt], 0,0,0);
  }
  #pragma unroll
  for (int nt=0;nt<4;nt++){
    int col = wl*64 + nt*16 + am;
    float bmv = bm[col];
    #pragma unroll
    for (int mt=0;mt<2;mt++){
      #pragma unroll
      for (int reg=0;reg<4;reg++){
        size_t p = p0 + wh*32 + mt*16 + aq*4 + reg;
        u2[p*DIM + col] = o[mt][nt][reg] + bmv + u[p*DIM + col];
      }
    }
  }
}

// ---------------------------------------------------------------- LN2 + MLP + residual (MFMA, in-place in d_out)
// 64 rows/block, 512 threads (8 waves = 2 row-halves x 4 col-quarters):
// row-halves share Wf1/Wf2 fragments -> per-row L2 weight traffic halved.
#define ML_STRIDE 264
__global__ void __launch_bounds__(512) k_mlp_out(float* u2,
    const float* __restrict__ g2, const float* __restrict__ b2,
    const short* __restrict__ Wf1P, const float* __restrict__ bf1,
    const short* __restrict__ Wf2P, const float* __restrict__ bf2){
  __shared__ __align__(16) short X[64*ML_STRIDE];   // 33.8 KB
  __shared__ __align__(16) short H[64*ML_STRIDE];   // 33.8 KB
  int tid = threadIdx.x;
  int lane = tid & 63, w = tid >> 6;
  int wh = w >> 2, wl = w & 3;
  size_t p0 = (size_t)blockIdx.x*64;

  float4 g4 = *(const float4*)&g2[lane*4];
  float4 bq4 = *(const float4*)&b2[lane*4];
  for (int rr=0; rr<8; rr++){
    int r = w*8 + rr;
    float4 v = *(const float4*)&u2[(p0 + r)*DIM + lane*4];
    float s = v.x+v.y+v.z+v.w;
    float ss = v.x*v.x+v.y*v.y+v.z*v.z+v.w*v.w;
    #pragma unroll
    for (int off=32;off>0;off>>=1){ s += __shfl_down(s,off,64); ss += __shfl_down(ss,off,64); }
    s = __shfl(s,0,64); ss = __shfl(ss,0,64);
    float m = s*(1.0f/DIM);
    float rstd = rsqrtf(ss*(1.0f/DIM) - m*m + 1e-5f);
    ushort4 xo;
    xo.x = (ushort)f2s((v.x-m)*rstd*g4.x + bq4.x);
    xo.y = (ushort)f2s((v.y-m)*rstd*g4.y + bq4.y);
    xo.z = (ushort)f2s((v.z-m)*rstd*g4.z + bq4.z);
    xo.w = (ushort)f2s((v.w-m)*rstd*g4.w + bq4.w);
    *(ushort4*)&X[r*ML_STRIDE + lane*4] = xo;
  }
  __syncthreads();

  int am = lane & 15, aq = lane >> 4;
  f32x4 o[2][4];
  #pragma unroll
  for (int mt=0;mt<2;mt++)
    #pragma unroll
    for (int nt=0;nt<4;nt++) o[mt][nt] = (f32x4){0.f,0.f,0.f,0.f};

  for (int nc=0; nc<4; nc++){
    f32x4 hacc[2][4];
    #pragma unroll
    for (int mt=0;mt<2;mt++)
      #pragma unroll
      for (int nt=0;nt<4;nt++) hacc[mt][nt] = (f32x4){0.f,0.f,0.f,0.f};
    for (int kb=0; kb<8; kb++){
      short8 a[2], bfr[4];
      #pragma unroll
      for (int mt=0;mt<2;mt++)
        a[mt] = *(const short8*)&X[(wh*32 + mt*16 + am)*ML_STRIDE + kb*32 + aq*8];
      #pragma unroll
      for (int nt=0;nt<4;nt++){
        int ntg = nc*16 + wl*4 + nt;
        bfr[nt] = *(const short8*)&Wf1P[(size_t)((kb*64 + ntg)*64 + lane)*8];
      }
      #pragma unroll
      for (int mt=0;mt<2;mt++)
        #pragma unroll
        for (int nt=0;nt<4;nt++)
          hacc[mt][nt] = __builtin_amdgcn_mfma_f32_16x16x32_bf16(a[mt], bfr[nt], hacc[mt][nt], 0,0,0);
    }
    #pragma unroll
    for (int nt=0;nt<4;nt++){
      int col_l = wl*64 + nt*16 + am;
      float bv = bf1[nc*256 + col_l];
      #pragma unroll
      for (int mt=0;mt<2;mt++){
        #pragma unroll
        for (int reg=0;reg<4;reg++){
          int row = wh*32 + mt*16 + aq*4 + reg;
          H[row*ML_STRIDE + col_l] = f2s(gelu_tanh(hacc[mt][nt][reg] + bv));
        }
      }
    }
    __syncthreads();
    for (int kb=0; kb<8; kb++){
      short8 a[2], bfr[4];
      #pragma unroll
      for (int mt=0;mt<2;mt++)
        a[mt] = *(const short8*)&H[(wh*32 + mt*16 + am)*ML_STRIDE + kb*32 + aq*8];
      int kbg = nc*8 + kb;
      #pragma unroll
      for (int nt=0;nt<4;nt++)
        bfr[nt] = *(const short8*)&Wf2P[(size_t)((kbg*16 + (wl*4+nt))*64 + lane)*8];
      #pragma unroll
      for (int mt=0;mt<2;mt++)
        #pragma unroll
        for (int nt=0;nt<4;nt++)
          o[mt][nt] = __builtin_amdgcn_mfma_f32_16x16x32_bf16(a[mt], bfr[nt], o[mt][nt], 0,0,0);
    }
    __syncthreads();
  }

  #pragma unroll
  for (int nt=0;nt<4;nt++){
    int col = wl*64 + nt*16 + am;
    float bv = bf2[col];
    #pragma unroll
    for (int mt=0;mt<2;mt++){
      #pragma unroll
      for (int reg=0;reg<4;reg++){
        size_t p = p0 + wh*32 + mt*16 + aq*4 + reg;
        float res = u2[p*DIM + col];
        u2[p*DIM + col] = o[mt][nt][reg] + bv + res;
      }
    }
  }
}

extern "C" void kernel_launch(void* const* d_in, const int* in_sizes, int n_in,
                              void* d_out, int out_size, void* d_ws, size_t ws_size,
                              hipStream_t stream){
  const float* u    = (const float*)d_in[0];
  const float* rcy  = (const float*)d_in[1];
  const float* rsy  = (const float*)d_in[2];
  const float* rcx  = (const float*)d_in[3];
  const float* rsx  = (const float*)d_in[4];
  const float* ln1g = (const float*)d_in[6];
  const float* ln1b = (const float*)d_in[7];
  const float* ln2g = (const float*)d_in[8];
  const float* ln2b = (const float*)d_in[9];
  const float* Wv   = (const float*)d_in[10];
  const float* Wyin = (const float*)d_in[11];
  const float* Wy1  = (const float*)d_in[12];
  const float* by1  = (const float*)d_in[13];
  const float* Wy2  = (const float*)d_in[14];
  const float* by2  = (const float*)d_in[15];
  const float* Wxin = (const float*)d_in[16];
  const float* Wx1  = (const float*)d_in[17];
  const float* bx1  = (const float*)d_in[18];
  const float* Wx2  = (const float*)d_in[19];
  const float* bx2  = (const float*)d_in[20];
  const float* Wqkx = (const float*)d_in[21];
  const float* Wqky = (const float*)d_in[22];
  const float* Wm   = (const float*)d_in[23];
  const float* bm   = (const float*)d_in[24];
  const float* Wf1  = (const float*)d_in[25];
  const float* bf1  = (const float*)d_in[26];
  const float* Wf2  = (const float*)d_in[27];
  const float* bf2  = (const float*)d_in[28];

  char* w = (char*)d_ws;
  auto alloc = [&](size_t n) -> void* {
    void* p = (void*)w;
    w += (n + 255) & ~(size_t)255;
    return p;
  };
  bf16_t* UN   = (bf16_t*)alloc((size_t)NPOS*DIM*2);               // 32 MiB
  bf16_t* PHI  = (bf16_t*)alloc((size_t)NB*NH*NY*NX*DH_*2);        // 64 MiB
  float* POOLY = (float*)alloc((size_t)NB*NY*DIM*4);
  float* POOLX = (float*)alloc((size_t)NB*NX*DIM*4);
  float* TY    = (float*)alloc((size_t)512*256*4);
  float* TX    = (float*)alloc((size_t)512*256*4);
  float* HY    = (float*)alloc((size_t)512*1024*4);
  float* HX    = (float*)alloc((size_t)512*1024*4);
  float* UY    = (float*)alloc((size_t)512*256*4);
  float* UX    = (float*)alloc((size_t)512*256*4);
  float* QKY   = (float*)alloc((size_t)512*1024*4);
  float* QKX   = (float*)alloc((size_t)512*1024*4);
  float* QRY   = (float*)alloc((size_t)NB*NH*128*64*4);
  float* KRY   = (float*)alloc((size_t)NB*NH*128*64*4);
  float* QRX   = (float*)alloc((size_t)NB*NH*128*64*4);
  float* KRX   = (float*)alloc((size_t)NB*NH*128*64*4);
  bf16_t* ATTNY = (bf16_t*)alloc((size_t)NB*NH*128*128*2);
  bf16_t* ATTNX = (bf16_t*)alloc((size_t)NB*NH*128*128*2);
  short* WF1P  = (short*)alloc((size_t)256*1024*2);
  short* WF2P  = (short*)alloc((size_t)1024*256*2);
  short* WMP   = (short*)alloc((size_t)512*256*2);
  short* WVP   = (short*)alloc((size_t)256*512*2);
  short* WYINP = (short*)alloc((size_t)256*256*2);
  short* WY1P  = (short*)alloc((size_t)256*1024*2);
  short* WY2P  = (short*)alloc((size_t)1024*256*2);
  short* WQKYP = (short*)alloc((size_t)256*1024*2);
  short* WXINP = (short*)alloc((size_t)256*256*2);
  short* WX1P  = (short*)alloc((size_t)256*1024*2);
  short* WX2P  = (short*)alloc((size_t)1024*256*2);
  short* WQKXP = (short*)alloc((size_t)256*1024*2);
  float* U2 = (float*)d_out;
  (void)in_sizes; (void)n_in; (void)out_size; (void)ws_size;

  k_pack<<<(256*1024/8)/256, 256, 0, stream>>>(Wf1, WF1P, 256, 1024);
  k_pack<<<(1024*256/8)/256, 256, 0, stream>>>(Wf2, WF2P, 1024, 256);
  k_pack<<<(512*256/8)/256, 256, 0, stream>>>(Wm, WMP, 512, 256);
  k_pack<<<(256*512/8)/256, 256, 0, stream>>>(Wv, WVP, 256, 512);
  k_pack<<<(256*256/8)/256, 256, 0, stream>>>(Wyin, WYINP, 256, 256);
  k_pack<<<(256*1024/8)/256, 256, 0, stream>>>(Wy1, WY1P, 256, 1024);
  k_pack<<<(1024*256/8)/256, 256, 0, stream>>>(Wy2, WY2P, 1024, 256);
  k_pack<<<(256*1024/8)/256, 256, 0, stream>>>(Wqky, WQKYP, 256, 1024);
  k_pack<<<(256*256/8)/256, 256, 0, stream>>>(Wxin, WXINP, 256, 256);
  k_pack<<<(256*1024/8)/256, 256, 0, stream>>>(Wx1, WX1P, 256, 1024);
  k_pack<<<(1024*256/8)/256, 256, 0, stream>>>(Wx2, WX2P, 1024, 256);
  k_pack<<<(256*1024/8)/256, 256, 0, stream>>>(Wqkx, WQKXP, 256, 1024);

  k_ln1<<<NPOS/4, 256, 0, stream>>>(u, ln1g, ln1b, UN);
  k_pool_y<<<NB*NY, 256, 0, stream>>>(UN, POOLY);
  k_pool_x<<<NB*NX, 256, 0, stream>>>(UN, POOLX);

  // y chain: pool -> Win -> gelu-MLP -> QK   (M=512 rows, MFMA)
  k_gemm_mfma<<<dim3(8,1), 256, 0, stream>>>(POOLY, WYINP, (const float*)nullptr, TY, 256, 256, 0);
  k_gemm_mfma<<<dim3(8,4), 256, 0, stream>>>(TY, WY1P, by1, HY, 1024, 256, 1);
  k_gemm_mfma<<<dim3(8,1), 256, 0, stream>>>(HY, WY2P, by2, UY, 256, 1024, 0);
  k_gemm_mfma<<<dim3(8,4), 256, 0, stream>>>(UY, WQKYP, (const float*)nullptr, QKY, 1024, 256, 0);
  // x chain
  k_gemm_mfma<<<dim3(8,1), 256, 0, stream>>>(POOLX, WXINP, (const float*)nullptr, TX, 256, 256, 0);
  k_gemm_mfma<<<dim3(8,4), 256, 0, stream>>>(TX, WX1P, bx1, HX, 1024, 256, 1);
  k_gemm_mfma<<<dim3(8,1), 256, 0, stream>>>(HX, WX2P, bx2, UX, 256, 1024, 0);
  k_gemm_mfma<<<dim3(8,4), 256, 0, stream>>>(UX, WQKXP, (const float*)nullptr, QKX, 1024, 256, 0);

  k_rope<<<(NB*128*1024)/256, 256, 0, stream>>>(QKY, rcy, rsy, QRY, KRY);
  k_rope<<<(NB*128*1024)/256, 256, 0, stream>>>(QKX, rcx, rsx, QRX, KRX);
  k_attn<<<NB*NH*128, 128, 0, stream>>>(QRY, KRY, ATTNY);
  k_attn<<<NB*NH*128, 128, 0, stream>>>(QRX, KRX, ATTNX);
  k_phi1m<<<NB*NH*NX, 256, 0, stream>>>(UN, WVP, ATTNY, PHI);
  k_phi2m<<<NB*NH*NY, 256, 0, stream>>>(ATTNX, PHI);
  k_gn_wm<<<NPOS/64, 512, 0, stream>>>(PHI, WMP, bm, u, U2);
  k_mlp_out<<<NPOS/64, 512, 0, stream>>>(U2, ln2g, ln2b, WF1P, bf1, WF2P, bf2);
}

// Round 5
// 610.498 us; speedup vs baseline: 3.3037x; 1.1125x over previous
//
#include <hip/hip_runtime.h>
#include <hip/hip_bf16.h>
#include <math.h>

// Problem constants (B=4, 128x128 grid, DIM=256, 8 heads x 64)
#define NB 4
#define NY 128
#define NX 128
#define DIM 256
#define NH 8
#define DH_ 64
#define HDIM 512   // NH*DH
#define HID 1024
#define NPOS (NB*NY*NX)   // 65536

typedef __hip_bfloat16 bf16_t;
typedef __attribute__((ext_vector_type(8))) short short8;   // 8 bf16 = 1 MFMA A/B frag
typedef __attribute__((ext_vector_type(4))) float f32x4;    // MFMA C/D frag

__device__ __forceinline__ float b2f(bf16_t x){ return __bfloat162float(x); }
__device__ __forceinline__ bf16_t f2b(float x){ return __float2bfloat16(x); }
__device__ __forceinline__ short f2s(float x){ bf16_t h = __float2bfloat16(x); return *reinterpret_cast<short*>(&h); }
__device__ __forceinline__ float s2f(short x){ bf16_t h = *reinterpret_cast<bf16_t*>(&x); return __bfloat162float(h); }

// MFMA fragment layout (gfx950, verified):
//  A[m][k]: m = lane&15, k = (lane>>4)*8 + j
//  B[k][n]: n = lane&15, k = (lane>>4)*8 + j
//  D[row][col]: col = lane&15, row = (lane>>4)*4 + reg

// gelu tanh-approx: 0.5x(1+tanh(t)) == x*sigmoid(2t); __expf maps to v_exp_f32.
__device__ __forceinline__ float gelu_tanh(float x){
  float z = 1.5957691216057308f*(x + 0.044715f*x*x*x);
  return x / (1.0f + __expf(-z));
}

// ---------------------------------------------------------------- weight pack
// W[K x N] f32 row-major -> bf16 B-fragment order
__global__ void __launch_bounds__(256) k_pack(const float* __restrict__ W,
    short* __restrict__ out, int K, int N){
  int tid = blockIdx.x*256 + threadIdx.x;      // < K*N/8
  int lane = tid & 63;
  int rem = tid >> 6;
  int ntiles = N >> 4;
  int nt = rem % ntiles, kb = rem / ntiles;
  int n = nt*16 + (lane & 15);
  int k0 = kb*32 + (lane>>4)*8;
  short8 v;
  #pragma unroll
  for (int j=0;j<8;j++) v[j] = f2s(W[(size_t)(k0+j)*N + n]);
  *(short8*)&out[(size_t)tid*8] = v;
}

// ---------------------------------------------------------------- LN1 (f32 in -> bf16 un)
__global__ void __launch_bounds__(256) k_ln1(const float* __restrict__ u,
    const float* __restrict__ g, const float* __restrict__ b,
    bf16_t* __restrict__ un){
  int wave = threadIdx.x >> 6, lane = threadIdx.x & 63;
  size_t row = (size_t)blockIdx.x*4 + wave;
  const float* x = u + row*DIM;
  float v[4]; float s=0.f, ss=0.f;
  #pragma unroll
  for (int j=0;j<4;j++){ float t = x[lane + j*64]; v[j]=t; s+=t; ss+=t*t; }
  #pragma unroll
  for (int off=32;off>0;off>>=1){ s += __shfl_down(s,off,64); ss += __shfl_down(ss,off,64); }
  s = __shfl(s,0,64); ss = __shfl(ss,0,64);
  float m = s*(1.0f/DIM);
  float var = ss*(1.0f/DIM) - m*m;
  float r = rsqrtf(var + 1e-5f);
  bf16_t* o = un + row*DIM;
  #pragma unroll
  for (int j=0;j<4;j++){
    int f = lane + j*64;
    o[f] = f2b((v[j]-m)*r*g[f] + b[f]);
  }
}

// ---------------------------------------------------------------- pooling (bf16 un -> f32)
__global__ void __launch_bounds__(256) k_pool_y(const bf16_t* __restrict__ un, float* __restrict__ pooly){
  int by = blockIdx.x;
  int d = threadIdx.x;
  size_t base = (size_t)by*NX*DIM + d;
  float s = 0.f;
  for (int x=0;x<NX;x++) s += b2f(un[base + (size_t)x*DIM]);
  pooly[(size_t)by*DIM + d] = s*(1.0f/NX);
}
__global__ void __launch_bounds__(256) k_pool_x(const bf16_t* __restrict__ un, float* __restrict__ poolx){
  int bb = blockIdx.x / NX, x = blockIdx.x % NX;
  int d = threadIdx.x;
  size_t base = ((size_t)bb*NY*NX + x)*DIM + d;
  float s = 0.f;
  for (int y=0;y<NY;y++) s += b2f(un[base + (size_t)y*NX*DIM]);
  poolx[(size_t)blockIdx.x*DIM + d] = s*(1.0f/NY);
}

// ---------------------------------------------------------------- MFMA GEMM, x/y chains fused via blockIdx.z
// C[M x N] = op(A[M x K] @ W + bias); grid = (M/64, N/256, 2), block 256.
#define GS_STRIDE 72
__global__ void __launch_bounds__(256) k_gemm2(const float* __restrict__ A0,
    const float* __restrict__ A1,
    const short* __restrict__ W0, const short* __restrict__ W1,
    const float* __restrict__ b0, const float* __restrict__ b1,
    float* __restrict__ C0, float* __restrict__ C1, int N, int K, int dogelu){
  const float* A  = blockIdx.z ? A1 : A0;
  const short* WP = blockIdx.z ? W1 : W0;
  const float* bias = blockIdx.z ? b1 : b0;
  float* C = blockIdx.z ? C1 : C0;
  __shared__ __align__(16) short As[64*GS_STRIDE];   // 9.2 KB
  int tid = threadIdx.x;
  int lane = tid & 63, w = tid >> 6;
  int am = lane & 15, aq = lane >> 4;
  int m0 = blockIdx.x*64;
  int nt0 = blockIdx.y*16;
  int ntiles = N >> 4;
  f32x4 o[4][4];
  #pragma unroll
  for (int mt=0;mt<4;mt++)
    #pragma unroll
    for (int nt=0;nt<4;nt++) o[mt][nt] = (f32x4){0.f,0.f,0.f,0.f};

  for (int kc=0; kc<K; kc+=64){
    #pragma unroll
    for (int it=0; it<4; it++){
      int q = tid + it*256;
      int r = q >> 4, c4 = q & 15;
      float4 v = *(const float4*)&A[(size_t)(m0+r)*K + kc + c4*4];
      ushort4 p;
      p.x = (ushort)f2s(v.x); p.y = (ushort)f2s(v.y);
      p.z = (ushort)f2s(v.z); p.w = (ushort)f2s(v.w);
      *(ushort4*)&As[r*GS_STRIDE + c4*4] = p;
    }
    __syncthreads();
    #pragma unroll
    for (int kb=0; kb<2; kb++){
      short8 a[4], bfr[4];
      #pragma unroll
      for (int mt=0;mt<4;mt++)
        a[mt] = *(const short8*)&As[(mt*16+am)*GS_STRIDE + kb*32 + aq*8];
      int kbg = (kc>>5) + kb;
      #pragma unroll
      for (int nt=0;nt<4;nt++){
        int ntg = nt0 + w*4 + nt;
        bfr[nt] = *(const short8*)&WP[(size_t)((kbg*ntiles + ntg)*64 + lane)*8];
      }
      #pragma unroll
      for (int mt=0;mt<4;mt++)
        #pragma unroll
        for (int nt=0;nt<4;nt++)
          o[mt][nt] = __builtin_amdgcn_mfma_f32_16x16x32_bf16(a[mt], bfr[nt], o[mt][nt], 0,0,0);
    }
    __syncthreads();
  }

  #pragma unroll
  for (int nt=0;nt<4;nt++){
    int col = (nt0 + w*4 + nt)*16 + am;
    float bv = bias ? bias[col] : 0.f;
    #pragma unroll
    for (int mt=0;mt<4;mt++){
      #pragma unroll
      for (int reg=0;reg<4;reg++){
        int row = m0 + mt*16 + aq*4 + reg;
        float val = o[mt][nt][reg] + bv;
        if (dogelu) val = gelu_tanh(val);
        C[(size_t)row*N + col] = val;
      }
    }
  }
}

// ---------------------------------------------------------------- RoPE split
__global__ void __launch_bounds__(256) k_rope(const float* __restrict__ qk,
    const float* __restrict__ cs, const float* __restrict__ sn,
    float* __restrict__ q, float* __restrict__ k){
  int idx = blockIdx.x*256 + threadIdx.x;
  int c = idx & 63;
  int h = (idx>>6) & 7;
  int p = (idx>>9) & 1;
  int n = (idx>>10) & 127;
  int bb = idx>>17;
  float t = qk[idx];
  float t2 = qk[(c<32) ? idx+32 : idx-32];
  if (c<32) t2 = -t2;
  float val = t*cs[n*64+c] + t2*sn[n*64+c];
  float* dst = p ? k : q;
  dst[(((size_t)bb*NH + h)*128 + n)*64 + c] = val;
}

// ---------------------------------------------------------------- attention matrix (bf16 out)
__global__ void __launch_bounds__(128) k_attn(const float* __restrict__ q,
    const float* __restrict__ k, bf16_t* __restrict__ attn){
  int i = blockIdx.x & 127;
  int bh = blockIdx.x >> 7;
  __shared__ float qs[64];
  __shared__ float sm[128];
  int tid = threadIdx.x;
  const float* qrow = q + ((size_t)bh*128 + i)*64;
  if (tid < 64) qs[tid] = qrow[tid];
  __syncthreads();
  const float* krow = k + ((size_t)bh*128 + tid)*64;
  float dot = 0.f;
  for (int c=0;c<64;c++) dot += qs[c]*krow[c];
  dot *= (1.0f/64.0f);
  sm[tid] = dot;
  __syncthreads();
  float mx = -1e30f;
  for (int j=0;j<128;j++) mx = fmaxf(mx, sm[j]);
  __syncthreads();
  float e = expf(dot - mx);
  sm[tid] = e;
  __syncthreads();
  float s = 0.f;
  for (int j=0;j<128;j++) s += sm[j];
  attn[(size_t)blockIdx.x*128 + tid] = f2b(e/s);
}

// ---------------------------------------------------------------- MFMA phi1: V-proj + y-attention
#define AST 136   // 128 + 8 shorts
#define UST 72    // 64 + 8 shorts
#define VST 136
__global__ void __launch_bounds__(256) k_phi1m(const bf16_t* __restrict__ un,
    const short* __restrict__ WvP, const bf16_t* __restrict__ attn,
    bf16_t* __restrict__ phi){
  int m  = blockIdx.x & (NX-1);
  int bh = blockIdx.x >> 7;
  int b  = bh >> 3, h = bh & 7;
  __shared__ __align__(16) short At[128*AST];   // 34.8 KB
  __shared__ __align__(16) short unc[128*UST];  // 18.4 KB
  __shared__ __align__(16) short Vt[64*VST];    // 17.4 KB  [c][y]
  int tid = threadIdx.x;
  int lane = tid & 63, w = tid >> 6;
  int am = lane & 15, aq = lane >> 4;

  {
    const ushort* ag = (const ushort*)attn + (size_t)bh*16384;
    #pragma unroll
    for (int it=0; it<16; it++){
      int q = tid + it*256;          // < 4096 ushort4
      int i = q >> 5, j4 = q & 31;
      *(ushort4*)&At[i*AST + j4*4] = *(const ushort4*)(ag + i*128 + j4*4);
    }
  }

  f32x4 v[2][4];
  #pragma unroll
  for (int mt=0;mt<2;mt++)
    #pragma unroll
    for (int nt=0;nt<4;nt++) v[mt][nt] = (f32x4){0.f,0.f,0.f,0.f};
  const ushort* ug = (const ushort*)un;
  for (int kc=0; kc<4; kc++){
    #pragma unroll
    for (int it=0; it<8; it++){
      int q = tid + it*256;          // < 2048 ushort4
      int y = q >> 4, c4 = q & 15;
      *(ushort4*)&unc[y*UST + c4*4] =
          *(const ushort4*)(ug + (((size_t)b*NY + y)*NX + m)*DIM + kc*64 + c4*4);
    }
    __syncthreads();
    #pragma unroll
    for (int kb=0; kb<2; kb++){
      short8 a2[2], bb[4];
      #pragma unroll
      for (int mt=0;mt<2;mt++)
        a2[mt] = *(const short8*)&unc[(w*32 + mt*16 + am)*UST + kb*32 + aq*8];
      int kbg = kc*2 + kb;           // of 8
      #pragma unroll
      for (int nt=0;nt<4;nt++)
        bb[nt] = *(const short8*)&WvP[(size_t)((kbg*32 + (h*4+nt))*64 + lane)*8];
      #pragma unroll
      for (int mt=0;mt<2;mt++)
        #pragma unroll
        for (int nt=0;nt<4;nt++)
          v[mt][nt] = __builtin_amdgcn_mfma_f32_16x16x32_bf16(a2[mt], bb[nt], v[mt][nt], 0,0,0);
    }
    __syncthreads();
  }
  #pragma unroll
  for (int mt=0;mt<2;mt++)
    #pragma unroll
    for (int nt=0;nt<4;nt++){
      int c = nt*16 + am;
      int y0 = w*32 + mt*16 + aq*4;
      ushort4 pk;
      pk.x = (ushort)f2s(v[mt][nt][0]);
      pk.y = (ushort)f2s(v[mt][nt][1]);
      pk.z = (ushort)f2s(v[mt][nt][2]);
      pk.w = (ushort)f2s(v[mt][nt][3]);
      *(ushort4*)&Vt[c*VST + y0] = pk;
    }
  __syncthreads();

  f32x4 o[2][4];
  #pragma unroll
  for (int mt=0;mt<2;mt++)
    #pragma unroll
    for (int nt=0;nt<4;nt++) o[mt][nt] = (f32x4){0.f,0.f,0.f,0.f};
  #pragma unroll
  for (int kb=0; kb<4; kb++){
    short8 a2[2], bb[4];
    #pragma unroll
    for (int mt=0;mt<2;mt++)
      a2[mt] = *(const short8*)&At[(w*32 + mt*16 + am)*AST + kb*32 + aq*8];
    #pragma unroll
    for (int nt=0;nt<4;nt++)
      bb[nt] = *(const short8*)&Vt[(nt*16 + am)*VST + kb*32 + aq*8];
    #pragma unroll
    for (int mt=0;mt<2;mt++)
      #pragma unroll
      for (int nt=0;nt<4;nt++)
        o[mt][nt] = __builtin_amdgcn_mfma_f32_16x16x32_bf16(a2[mt], bb[nt], o[mt][nt], 0,0,0);
  }
  ushort* pg = (ushort*)phi + (size_t)bh*NY*NX*DH_ + (size_t)m*DH_;
  #pragma unroll
  for (int mt=0;mt<2;mt++)
    #pragma unroll
    for (int nt=0;nt<4;nt++)
      #pragma unroll
      for (int reg=0;reg<4;reg++){
        int i = w*32 + mt*16 + aq*4 + reg;
        int c = nt*16 + am;
        pg[(size_t)i*(NX*DH_) + c] = (ushort)f2s(o[mt][nt][reg]);
      }
}

// ---------------------------------------------------------------- MFMA phi2: x-attention, in place
__global__ void __launch_bounds__(256) k_phi2m(const bf16_t* __restrict__ attn,
    bf16_t* __restrict__ phi){
  int i  = blockIdx.x & (NY-1);
  int bh = blockIdx.x >> 7;
  __shared__ __align__(16) short Ax[128*AST];   // 34.8 KB
  __shared__ __align__(16) short Pt[64*VST];    // 17.4 KB  [c][m]
  int tid = threadIdx.x;
  int lane = tid & 63, w = tid >> 6;
  int am = lane & 15, aq = lane >> 4;

  {
    const ushort* ag = (const ushort*)attn + (size_t)bh*16384;
    #pragma unroll
    for (int it=0; it<16; it++){
      int q = tid + it*256;
      int r = q >> 5, j4 = q & 31;
      *(ushort4*)&Ax[r*AST + j4*4] = *(const ushort4*)(ag + r*128 + j4*4);
    }
  }
  ushort* pg = (ushort*)phi + (size_t)(bh*NY + i)*(NX*DH_);
  #pragma unroll
  for (int it=0; it<8; it++){
    int q = tid + it*256;            // < 2048 ushort4
    int mm = q >> 4, c4 = q & 15;
    ushort4 v4 = *(const ushort4*)(pg + mm*DH_ + c4*4);
    Pt[(c4*4+0)*VST + mm] = v4.x;
    Pt[(c4*4+1)*VST + mm] = v4.y;
    Pt[(c4*4+2)*VST + mm] = v4.z;
    Pt[(c4*4+3)*VST + mm] = v4.w;
  }
  __syncthreads();

  f32x4 o[2][4];
  #pragma unroll
  for (int mt=0;mt<2;mt++)
    #pragma unroll
    for (int nt=0;nt<4;nt++) o[mt][nt] = (f32x4){0.f,0.f,0.f,0.f};
  #pragma unroll
  for (int kb=0; kb<4; kb++){
    short8 a2[2], bb[4];
    #pragma unroll
    for (int mt=0;mt<2;mt++)
      a2[mt] = *(const short8*)&Ax[(w*32 + mt*16 + am)*AST + kb*32 + aq*8];
    #pragma unroll
    for (int nt=0;nt<4;nt++)
      bb[nt] = *(const short8*)&Pt[(nt*16 + am)*VST + kb*32 + aq*8];
    #pragma unroll
    for (int mt=0;mt<2;mt++)
      #pragma unroll
      for (int nt=0;nt<4;nt++)
        o[mt][nt] = __builtin_amdgcn_mfma_f32_16x16x32_bf16(a2[mt], bb[nt], o[mt][nt], 0,0,0);
  }
  #pragma unroll
  for (int mt=0;mt<2;mt++)
    #pragma unroll
    for (int nt=0;nt<4;nt++)
      #pragma unroll
      for (int reg=0;reg<4;reg++){
        int l = w*32 + mt*16 + aq*4 + reg;
        int c = nt*16 + am;
        pg[(size_t)l*DH_ + c] = (ushort)f2s(o[mt][nt][reg]);
      }
}

// ---------------------------------------------------------------- fused tail:
// GN(phi) -> @Wm+bm+u (u2 in REGS, never leaves the kernel) -> LN2 (reg-level
// stats, shfl+LDS cross-wave) -> MLP (acc initialized with u2 = fused residual)
// -> out. Removes u2 HBM round-trips (~190 MB) and one dispatch.
// 512 threads = 8 waves (wh = row-half, wl = col-quarter). 64 rows/block.
#define GN_ST 520
#define ML_ST 264
__global__ void __launch_bounds__(512, 4) k_tail(const bf16_t* __restrict__ phi,
    const short* __restrict__ WmP, const float* __restrict__ bm,
    const float* __restrict__ u,
    const float* __restrict__ g2, const float* __restrict__ b2,
    const short* __restrict__ Wf1P, const float* __restrict__ bf1,
    const short* __restrict__ Wf2P, const float* __restrict__ bf2,
    float* __restrict__ out){
  __shared__ __align__(16) short SMEM[64*ML_ST*2];   // 67.6 KB: Xg | (Xm , H)
  __shared__ float mean_s[512], rstd_s[512];         // GN stats
  __shared__ float prow[64][4], prow2[64][4];        // LN2 per-wl partials
  __shared__ float mrow[64], rrow[64];
  short* Xg = SMEM;             // [64][GN_ST]  (66.6 KB <= 67.6)
  short* Xm = SMEM;             // [64][ML_ST]
  short* H  = SMEM + 64*ML_ST;  // [64][ML_ST]
  int tid = threadIdx.x;
  int lane = tid & 63, w = tid >> 6;
  int wh = w >> 2, wl = w & 3;
  int am = lane & 15, aq = lane >> 4;
  size_t p0 = (size_t)blockIdx.x*64;
  int b  = (int)(p0 >> 14);
  int y  = (int)((p0 >> 7) & 127);
  int x0 = (int)(p0 & 127);

  // ---- stage phi -> Xg
  #pragma unroll
  for (int it=0; it<16; it++){
    int q = tid + it*512;            // < 8192 ushort4
    int r = q >> 7, f4 = q & 127;
    int h = f4 >> 4, c4 = f4 & 15;
    const ushort* src = (const ushort*)phi +
        ((((size_t)b*NH + h)*NY + y)*NX + (x0 + r))*DH_ + c4*4;
    *(ushort4*)&Xg[r*GN_ST + f4*4] = *(const ushort4*)src;
  }
  __syncthreads();
  // ---- GN stats: 512 groups (64 rows x 8 heads), 1 thread each
  {
    int g = tid;
    int r = g >> 3, h = g & 7;
    const short* base = &Xg[r*GN_ST + h*64];
    float s=0.f, ss=0.f;
    #pragma unroll
    for (int i=0;i<16;i++){
      ushort4 v4 = *(const ushort4*)&base[i*4];
      float a = s2f((short)v4.x), bq = s2f((short)v4.y), cq = s2f((short)v4.z), d = s2f((short)v4.w);
      s += a+bq+cq+d; ss += a*a+bq*bq+cq*cq+d*d;
    }
    float mm = s*(1.0f/64.0f);
    float vv = ss*(1.0f/64.0f) - mm*mm;
    mean_s[g] = mm;
    rstd_s[g] = rsqrtf(vv + 1e-6f);
  }
  __syncthreads();
  // ---- normalize Xg in place
  #pragma unroll
  for (int it=0; it<16; it++){
    int q = tid + it*512;
    int r = q >> 7, f4 = q & 127;
    int h = f4 >> 4;
    float mm = mean_s[r*8 + h], rs = rstd_s[r*8 + h];
    short* ptr = &Xg[r*GN_ST + f4*4];
    ushort4 v4 = *(ushort4*)ptr;
    v4.x = (ushort)f2s((s2f((short)v4.x)-mm)*rs);
    v4.y = (ushort)f2s((s2f((short)v4.y)-mm)*rs);
    v4.z = (ushort)f2s((s2f((short)v4.z)-mm)*rs);
    v4.w = (ushort)f2s((s2f((short)v4.w)-mm)*rs);
    *(ushort4*)ptr = v4;
  }
  __syncthreads();

  // ---- Wm GEMM -> u2 regs (+bm +u residual)
  f32x4 u2r[2][4];
  #pragma unroll
  for (int mt=0;mt<2;mt++)
    #pragma unroll
    for (int nt=0;nt<4;nt++) u2r[mt][nt] = (f32x4){0.f,0.f,0.f,0.f};
  for (int kb=0; kb<16; kb++){
    short8 a[2], bfr[4];
    #pragma unroll
    for (int mt=0;mt<2;mt++)
      a[mt] = *(const short8*)&Xg[(wh*32 + mt*16 + am)*GN_ST + kb*32 + aq*8];
    #pragma unroll
    for (int nt=0;nt<4;nt++)
      bfr[nt] = *(const short8*)&WmP[(size_t)((kb*16 + (wl*4+nt))*64 + lane)*8];
    #pragma unroll
    for (int mt=0;mt<2;mt++)
      #pragma unroll
      for (int nt=0;nt<4;nt++)
        u2r[mt][nt] = __builtin_amdgcn_mfma_f32_16x16x32_bf16(a[mt], bfr[nt], u2r[mt][nt], 0,0,0);
  }
  #pragma unroll
  for (int nt=0;nt<4;nt++){
    int col = wl*64 + nt*16 + am;
    float bmv = bm[col];
    #pragma unroll
    for (int mt=0;mt<2;mt++){
      #pragma unroll
      for (int reg=0;reg<4;reg++){
        size_t p = p0 + wh*32 + mt*16 + aq*4 + reg;
        u2r[mt][nt][reg] += bmv + u[p*DIM + col];
      }
    }
  }

  // ---- LN2 stats from regs: butterfly over 16-lane (am) group, combine wl via LDS
  #pragma unroll
  for (int mt=0;mt<2;mt++){
    #pragma unroll
    for (int reg=0;reg<4;reg++){
      float s  = u2r[mt][0][reg]+u2r[mt][1][reg]+u2r[mt][2][reg]+u2r[mt][3][reg];
      float ss = u2r[mt][0][reg]*u2r[mt][0][reg]+u2r[mt][1][reg]*u2r[mt][1][reg]
               + u2r[mt][2][reg]*u2r[mt][2][reg]+u2r[mt][3][reg]*u2r[mt][3][reg];
      #pragma unroll
      for (int msk=1; msk<16; msk<<=1){
        s  += __shfl_xor(s,  msk, 64);
        ss += __shfl_xor(ss, msk, 64);
      }
      if (am == 0){
        int r = wh*32 + mt*16 + aq*4 + reg;
        prow[r][wl] = s;
        prow2[r][wl] = ss;
      }
    }
  }
  __syncthreads();
  if (tid < 64){
    float s  = prow[tid][0]+prow[tid][1]+prow[tid][2]+prow[tid][3];
    float ss = prow2[tid][0]+prow2[tid][1]+prow2[tid][2]+prow2[tid][3];
    float m = s*(1.0f/DIM);
    mrow[tid] = m;
    rrow[tid] = rsqrtf(ss*(1.0f/DIM) - m*m + 1e-5f);
  }
  __syncthreads();
  // ---- normalize -> Xm (reuses Xg space; all waves past the Wm GEMM by now)
  #pragma unroll
  for (int nt=0;nt<4;nt++){
    int col = wl*64 + nt*16 + am;
    float gg = g2[col], bb2 = b2[col];
    #pragma unroll
    for (int mt=0;mt<2;mt++){
      #pragma unroll
      for (int reg=0;reg<4;reg++){
        int r = wh*32 + mt*16 + aq*4 + reg;
        Xm[r*ML_ST + col] = f2s((u2r[mt][nt][reg]-mrow[r])*rrow[r]*gg + bb2);
      }
    }
  }
  __syncthreads();

  // ---- MLP: acc o2 initialized with u2r (fused residual, frees u2r regs)
  f32x4 o2[2][4];
  #pragma unroll
  for (int mt=0;mt<2;mt++)
    #pragma unroll
    for (int nt=0;nt<4;nt++) o2[mt][nt] = u2r[mt][nt];

  for (int nc=0; nc<4; nc++){
    f32x4 hacc[2][4];
    #pragma unroll
    for (int mt=0;mt<2;mt++)
      #pragma unroll
      for (int nt=0;nt<4;nt++) hacc[mt][nt] = (f32x4){0.f,0.f,0.f,0.f};
    for (int kb=0; kb<8; kb++){
      short8 a[2], bfr[4];
      #pragma unroll
      for (int mt=0;mt<2;mt++)
        a[mt] = *(const short8*)&Xm[(wh*32 + mt*16 + am)*ML_ST + kb*32 + aq*8];
      #pragma unroll
      for (int nt=0;nt<4;nt++){
        int ntg = nc*16 + wl*4 + nt;
        bfr[nt] = *(const short8*)&Wf1P[(size_t)((kb*64 + ntg)*64 + lane)*8];
      }
      #pragma unroll
      for (int mt=0;mt<2;mt++)
        #pragma unroll
        for (int nt=0;nt<4;nt++)
          hacc[mt][nt] = __builtin_amdgcn_mfma_f32_16x16x32_bf16(a[mt], bfr[nt], hacc[mt][nt], 0,0,0);
    }
    #pragma unroll
    for (int nt=0;nt<4;nt++){
      int col_l = wl*64 + nt*16 + am;
      float bv = bf1[nc*256 + col_l];
      #pragma unroll
      for (int mt=0;mt<2;mt++){
        #pragma unroll
        for (int reg=0;reg<4;reg++){
          int row = wh*32 + mt*16 + aq*4 + reg;
          H[row*ML_ST + col_l] = f2s(gelu_tanh(hacc[mt][nt][reg] + bv));
        }
      }
    }
    __syncthreads();
    for (int kb=0; kb<8; kb++){
      short8 a[2], bfr[4];
      #pragma unroll
      for (int mt=0;mt<2;mt++)
        a[mt] = *(const short8*)&H[(wh*32 + mt*16 + am)*ML_ST + kb*32 + aq*8];
      int kbg = nc*8 + kb;
      #pragma unroll
      for (int nt=0;nt<4;nt++)
        bfr[nt] = *(const short8*)&Wf2P[(size_t)((kbg*16 + (wl*4+nt))*64 + lane)*8];
      #pragma unroll
      for (int mt=0;mt<2;mt++)
        #pragma unroll
        for (int nt=0;nt<4;nt++)
          o2[mt][nt] = __builtin_amdgcn_mfma_f32_16x16x32_bf16(a[mt], bfr[nt], o2[mt][nt], 0,0,0);
    }
    __syncthreads();
  }

  // ---- epilogue: out = o2 (includes u2 residual) + bf2
  #pragma unroll
  for (int nt=0;nt<4;nt++){
    int col = wl*64 + nt*16 + am;
    float bv = bf2[col];
    #pragma unroll
    for (int mt=0;mt<2;mt++){
      #pragma unroll
      for (int reg=0;reg<4;reg++){
        size_t p = p0 + wh*32 + mt*16 + aq*4 + reg;
        out[p*DIM + col] = o2[mt][nt][reg] + bv;
      }
    }
  }
}

extern "C" void kernel_launch(void* const* d_in, const int* in_sizes, int n_in,
                              void* d_out, int out_size, void* d_ws, size_t ws_size,
                              hipStream_t stream){
  const float* u    = (const float*)d_in[0];
  const float* rcy  = (const float*)d_in[1];
  const float* rsy  = (const float*)d_in[2];
  const float* rcx  = (const float*)d_in[3];
  const float* rsx  = (const float*)d_in[4];
  const float* ln1g = (const float*)d_in[6];
  const float* ln1b = (const float*)d_in[7];
  const float* ln2g = (const float*)d_in[8];
  const float* ln2b = (const float*)d_in[9];
  const float* Wv   = (const float*)d_in[10];
  const float* Wyin = (const float*)d_in[11];
  const float* Wy1  = (const float*)d_in[12];
  const float* by1  = (const float*)d_in[13];
  const float* Wy2  = (const float*)d_in[14];
  const float* by2  = (const float*)d_in[15];
  const float* Wxin = (const float*)d_in[16];
  const float* Wx1  = (const float*)d_in[17];
  const float* bx1  = (const float*)d_in[18];
  const float* Wx2  = (const float*)d_in[19];
  const float* bx2  = (const float*)d_in[20];
  const float* Wqkx = (const float*)d_in[21];
  const float* Wqky = (const float*)d_in[22];
  const float* Wm   = (const float*)d_in[23];
  const float* bm   = (const float*)d_in[24];
  const float* Wf1  = (const float*)d_in[25];
  const float* bf1  = (const float*)d_in[26];
  const float* Wf2  = (const float*)d_in[27];
  const float* bf2  = (const float*)d_in[28];

  char* w = (char*)d_ws;
  auto alloc = [&](size_t n) -> void* {
    void* p = (void*)w;
    w += (n + 255) & ~(size_t)255;
    return p;
  };
  bf16_t* UN   = (bf16_t*)alloc((size_t)NPOS*DIM*2);               // 32 MiB
  bf16_t* PHI  = (bf16_t*)alloc((size_t)NB*NH*NY*NX*DH_*2);        // 64 MiB
  float* POOLY = (float*)alloc((size_t)NB*NY*DIM*4);
  float* POOLX = (float*)alloc((size_t)NB*NX*DIM*4);
  float* TY    = (float*)alloc((size_t)512*256*4);
  float* TX    = (float*)alloc((size_t)512*256*4);
  float* HY    = (float*)alloc((size_t)512*1024*4);
  float* HX    = (float*)alloc((size_t)512*1024*4);
  float* UY    = (float*)alloc((size_t)512*256*4);
  float* UX    = (float*)alloc((size_t)512*256*4);
  float* QKY   = (float*)alloc((size_t)512*1024*4);
  float* QKX   = (float*)alloc((size_t)512*1024*4);
  float* QRY   = (float*)alloc((size_t)NB*NH*128*64*4);
  float* KRY   = (float*)alloc((size_t)NB*NH*128*64*4);
  float* QRX   = (float*)alloc((size_t)NB*NH*128*64*4);
  float* KRX   = (float*)alloc((size_t)NB*NH*128*64*4);
  bf16_t* ATTNY = (bf16_t*)alloc((size_t)NB*NH*128*128*2);
  bf16_t* ATTNX = (bf16_t*)alloc((size_t)NB*NH*128*128*2);
  short* WF1P  = (short*)alloc((size_t)256*1024*2);
  short* WF2P  = (short*)alloc((size_t)1024*256*2);
  short* WMP   = (short*)alloc((size_t)512*256*2);
  short* WVP   = (short*)alloc((size_t)256*512*2);
  short* WYINP = (short*)alloc((size_t)256*256*2);
  short* WY1P  = (short*)alloc((size_t)256*1024*2);
  short* WY2P  = (short*)alloc((size_t)1024*256*2);
  short* WQKYP = (short*)alloc((size_t)256*1024*2);
  short* WXINP = (short*)alloc((size_t)256*256*2);
  short* WX1P  = (short*)alloc((size_t)256*1024*2);
  short* WX2P  = (short*)alloc((size_t)1024*256*2);
  short* WQKXP = (short*)alloc((size_t)256*1024*2);
  float* U2 = (float*)d_out;
  (void)in_sizes; (void)n_in; (void)out_size; (void)ws_size;

  k_pack<<<(256*1024/8)/256, 256, 0, stream>>>(Wf1, WF1P, 256, 1024);
  k_pack<<<(1024*256/8)/256, 256, 0, stream>>>(Wf2, WF2P, 1024, 256);
  k_pack<<<(512*256/8)/256, 256, 0, stream>>>(Wm, WMP, 512, 256);
  k_pack<<<(256*512/8)/256, 256, 0, stream>>>(Wv, WVP, 256, 512);
  k_pack<<<(256*256/8)/256, 256, 0, stream>>>(Wyin, WYINP, 256, 256);
  k_pack<<<(256*1024/8)/256, 256, 0, stream>>>(Wy1, WY1P, 256, 1024);
  k_pack<<<(1024*256/8)/256, 256, 0, stream>>>(Wy2, WY2P, 1024, 256);
  k_pack<<<(256*1024/8)/256, 256, 0, stream>>>(Wqky, WQKYP, 256, 1024);
  k_pack<<<(256*256/8)/256, 256, 0, stream>>>(Wxin, WXINP, 256, 256);
  k_pack<<<(256*1024/8)/256, 256, 0, stream>>>(Wx1, WX1P, 256, 1024);
  k_pack<<<(1024*256/8)/256, 256, 0, stream>>>(Wx2, WX2P, 1024, 256);
  k_pack<<<(256*1024/8)/256, 256, 0, stream>>>(Wqkx, WQKXP, 256, 1024);

  k_ln1<<<NPOS/4, 256, 0, stream>>>(u, ln1g, ln1b, UN);
  k_pool_y<<<NB*NY, 256, 0, stream>>>(UN, POOLY);
  k_pool_x<<<NB*NX, 256, 0, stream>>>(UN, POOLX);

  // x/y chains fused via grid.z: pool -> Win -> gelu-MLP -> QK
  k_gemm2<<<dim3(8,1,2), 256, 0, stream>>>(POOLY, POOLX, WYINP, WXINP,
      (const float*)nullptr, (const float*)nullptr, TY, TX, 256, 256, 0);
  k_gemm2<<<dim3(8,4,2), 256, 0, stream>>>(TY, TX, WY1P, WX1P, by1, bx1, HY, HX, 1024, 256, 1);
  k_gemm2<<<dim3(8,1,2), 256, 0, stream>>>(HY, HX, WY2P, WX2P, by2, bx2, UY, UX, 256, 1024, 0);
  k_gemm2<<<dim3(8,4,2), 256, 0, stream>>>(UY, UX, WQKYP, WQKXP,
      (const float*)nullptr, (const float*)nullptr, QKY, QKX, 1024, 256, 0);

  k_rope<<<(NB*128*1024)/256, 256, 0, stream>>>(QKY, rcy, rsy, QRY, KRY);
  k_rope<<<(NB*128*1024)/256, 256, 0, stream>>>(QKX, rcx, rsx, QRX, KRX);
  k_attn<<<NB*NH*128, 128, 0, stream>>>(QRY, KRY, ATTNY);
  k_attn<<<NB*NH*128, 128, 0, stream>>>(QRX, KRX, ATTNX);
  k_phi1m<<<NB*NH*NX, 256, 0, stream>>>(UN, WVP, ATTNY, PHI);
  k_phi2m<<<NB*NH*NY, 256, 0, stream>>>(ATTNX, PHI);
  k_tail<<<NPOS/64, 512, 0, stream>>>(PHI, WMP, bm, u, ln2g, ln2b,
      WF1P, bf1, WF2P, bf2, U2);
}